// Round 3
// baseline (489.451 us; speedup 1.0000x reference)
//
#include <hip/hip_runtime.h>

#define IN_FEATS 256
#define HID 32
#define OUT_FEATS 256
#define NUM_EMBED 54012
#define N_NODES 65536
#define N_EDGES 1048576
#define BATCH 4096

#define NBUCK 1024          // dst >> 6
#define BSHIFT 6
#define BLOW 63
#define NODES_PER_BUCK 64
#define CAP 256             // per (group,bucket) capacity; mean 128, sd ~11
#define NGROUP 8

// ---------------------------------------------------------------------------
// K1: tmp[r][c] = sum_k embed[r][k] * W1[k][c]   (54012 x 32)
// 256 threads = 32 row-groups x 8 col-groups; each thread does 4 rows x 4 cols.
// ---------------------------------------------------------------------------
__global__ void k_embed_w1(const float* __restrict__ embed,
                           const float* __restrict__ W1,
                           float* __restrict__ tmp) {
    __shared__ float w1s[IN_FEATS * HID];
    int tid = threadIdx.x;
    for (int i = tid; i < IN_FEATS * HID / 4; i += 256)
        ((float4*)w1s)[i] = ((const float4*)W1)[i];
    __syncthreads();

    int rg = tid >> 3;                    // 0..31
    int cg = tid & 7;                     // 0..7
    int r0 = blockIdx.x * 128 + rg * 4;
    int c0 = cg * 4;

    int ra = min(r0 + 0, NUM_EMBED - 1);
    int rb = min(r0 + 1, NUM_EMBED - 1);
    int rc = min(r0 + 2, NUM_EMBED - 1);
    int rd = min(r0 + 3, NUM_EMBED - 1);
    const float4* E0 = (const float4*)(embed + (size_t)ra * IN_FEATS);
    const float4* E1 = (const float4*)(embed + (size_t)rb * IN_FEATS);
    const float4* E2 = (const float4*)(embed + (size_t)rc * IN_FEATS);
    const float4* E3 = (const float4*)(embed + (size_t)rd * IN_FEATS);

    float4 a0 = {0,0,0,0}, a1 = {0,0,0,0}, a2 = {0,0,0,0}, a3 = {0,0,0,0};

#define FMA4(ACC, S, W) \
    ACC.x += (S) * (W).x; ACC.y += (S) * (W).y; ACC.z += (S) * (W).z; ACC.w += (S) * (W).w;

    for (int k4 = 0; k4 < IN_FEATS / 4; ++k4) {
        float4 e0 = E0[k4], e1 = E1[k4], e2 = E2[k4], e3 = E3[k4];
        const float4* wr = (const float4*)(w1s + (k4 * 4) * HID) + cg;
        float4 w;
        w = wr[0];  FMA4(a0, e0.x, w) FMA4(a1, e1.x, w) FMA4(a2, e2.x, w) FMA4(a3, e3.x, w)
        w = wr[8];  FMA4(a0, e0.y, w) FMA4(a1, e1.y, w) FMA4(a2, e2.y, w) FMA4(a3, e3.y, w)
        w = wr[16]; FMA4(a0, e0.z, w) FMA4(a1, e1.z, w) FMA4(a2, e2.z, w) FMA4(a3, e3.z, w)
        w = wr[24]; FMA4(a0, e0.w, w) FMA4(a1, e1.w, w) FMA4(a2, e2.w, w) FMA4(a3, e3.w, w)
    }
#undef FMA4

    if (r0 + 0 < NUM_EMBED) *(float4*)(tmp + (size_t)(r0 + 0) * HID + c0) = a0;
    if (r0 + 1 < NUM_EMBED) *(float4*)(tmp + (size_t)(r0 + 1) * HID + c0) = a1;
    if (r0 + 2 < NUM_EMBED) *(float4*)(tmp + (size_t)(r0 + 2) * HID + c0) = a2;
    if (r0 + 3 < NUM_EMBED) *(float4*)(tmp + (size_t)(r0 + 3) * HID + c0) = a3;
}

// ---------------------------------------------------------------------------
// K2: feat1[n][:] = tmp[idx[n]][:]
// ---------------------------------------------------------------------------
__global__ void k_gather(const float* __restrict__ tmp,
                         const int* __restrict__ idx,
                         float* __restrict__ feat1) {
    int t = blockIdx.x * 256 + threadIdx.x;
    int n = t >> 3;
    int c = (t & 7) * 4;
    if (n >= N_NODES) return;
    int e = idx[n];
    float4 v = *(const float4*)(tmp + (size_t)e * HID + c);
    *(float4*)(feat1 + (size_t)n * HID + c) = v;
}

// ---------------------------------------------------------------------------
// K_bin: scatter edges into (group, bucket) lists. group = blockIdx&7 keeps
// each group's bucket-tail cache lines XCD-local (write-combine in L2).
// packed word: src (16b) | (dst & 63) << 16
// ---------------------------------------------------------------------------
__global__ void k_bin(const int* __restrict__ src, const int* __restrict__ dst,
                      int* __restrict__ cnt, int* __restrict__ bins) {
    int g = blockIdx.x & 7;
    int t = blockIdx.x * 256 + threadIdx.x;
    for (int e = t; e < N_EDGES; e += 2048 * 256) {
        int s = src[e], d = dst[e];
        int b = d >> BSHIFT;
        int gi = g * NBUCK + b;
        int pos = atomicAdd(&cnt[gi], 1);
        if (pos < CAP)
            bins[(gi << 8) + pos] = s | ((d & BLOW) << 16);
    }
}

// ---------------------------------------------------------------------------
// Binned SpMM: one block per bucket (64 dst nodes), LDS f32 accumulator.
// 256 threads: c = tid&31 (col), w = tid>>5 (edge slot group).
// out[v][c] = (relu? relu(sum + b1[c]) : sum)
// ---------------------------------------------------------------------------
template <int RELU>
__global__ void k_spmm_binned(const float* __restrict__ feat,
                              const int* __restrict__ cnt,
                              const int* __restrict__ bins,
                              const float* __restrict__ b1,
                              float* __restrict__ out) {
    __shared__ float acc[NODES_PER_BUCK * HID];   // 8 KB
    int b = blockIdx.x;
    int tid = threadIdx.x;
    for (int i = tid; i < NODES_PER_BUCK * HID; i += 256) acc[i] = 0.f;
    __syncthreads();

    int c = tid & 31;
    int w = tid >> 5;                              // 0..7

    for (int g = 0; g < NGROUP; ++g) {
        int gi = g * NBUCK + b;
        int n = cnt[gi];
        if (n > CAP) n = CAP;
        const int* base = bins + (gi << 8);
        for (int j = w; j < n; j += 8) {
            int p = base[j];
            int s = p & 0xFFFF;
            int r = p >> 16;
            float v = feat[((size_t)s << 5) + c];
            atomicAdd(&acc[(r << 5) + c], v);
        }
    }
    __syncthreads();

    float bias = RELU ? b1[c] : 0.f;
    for (int r = w; r < NODES_PER_BUCK; r += 8) {
        float v = acc[(r << 5) + c] + bias;
        if (RELU) v = fmaxf(v, 0.f);
        out[((size_t)(b * NODES_PER_BUCK + r) << 5) + c] = v;
    }
}

// ---------------------------------------------------------------------------
// K6: fold W2/Wfc/b2/bfc into M1[32,256], M2[32,256], bias[256]
// ---------------------------------------------------------------------------
__global__ void k_fold(const float* __restrict__ W2, const float* __restrict__ b2,
                       const float* __restrict__ Wfc, const float* __restrict__ bfc,
                       float* __restrict__ M1, float* __restrict__ M2,
                       float* __restrict__ bias) {
    int c = threadIdx.x;
    int r = blockIdx.x;
    if (r < 32) {
        float acc = 0.f;
        for (int j = 0; j < 256; ++j) acc += W2[r * 256 + j] * Wfc[j * 256 + c];
        M1[r * 256 + c] = acc;
    } else if (r < 64) {
        int k = r - 32;
        float acc = 0.f;
        for (int j = 0; j < 256; ++j) acc += W2[k * 256 + j] * Wfc[(256 + j) * 256 + c];
        M2[k * 256 + c] = acc;
    } else {
        float acc = bfc[c];
        for (int j = 0; j < 256; ++j) acc += b2[j] * (Wfc[j * 256 + c] + Wfc[(256 + j) * 256 + c]);
        bias[c] = acc;
    }
}

// ---------------------------------------------------------------------------
// K7: out[i][c] = relu(agg2[g1[i]] @ M1[:,c] + agg2[g2[i]] @ M2[:,c] + bias[c])
// ---------------------------------------------------------------------------
__global__ void k_final(const float* __restrict__ agg2,
                        const int* __restrict__ g1, const int* __restrict__ g2,
                        const float* __restrict__ M1, const float* __restrict__ M2,
                        const float* __restrict__ bias,
                        float* __restrict__ out) {
    __shared__ float a1s[HID];
    __shared__ float a2s[HID];
    int i = blockIdx.x;
    int c = threadIdx.x;
    if (c < 32) a1s[c] = agg2[(size_t)g1[i] * HID + c];
    else if (c < 64) a2s[c - 32] = agg2[(size_t)g2[i] * HID + (c - 32)];
    __syncthreads();

    float acc = bias[c];
#pragma unroll
    for (int k = 0; k < HID; ++k) {
        acc += a1s[k] * M1[k * 256 + c];
        acc += a2s[k] * M2[k * 256 + c];
    }
    out[(size_t)i * 256 + c] = fmaxf(acc, 0.f);
}

// ---------------------------------------------------------------------------
extern "C" void kernel_launch(void* const* d_in, const int* in_sizes, int n_in,
                              void* d_out, int out_size, void* d_ws, size_t ws_size,
                              hipStream_t stream) {
    const int*   idx   = (const int*)d_in[0];
    const int*   src   = (const int*)d_in[1];
    const int*   dst   = (const int*)d_in[2];
    const int*   g1    = (const int*)d_in[3];
    const int*   g2    = (const int*)d_in[4];
    const float* embed = (const float*)d_in[5];
    const float* W1    = (const float*)d_in[6];
    const float* b1    = (const float*)d_in[7];
    const float* W2    = (const float*)d_in[8];
    const float* b2    = (const float*)d_in[9];
    const float* Wfc   = (const float*)d_in[10];
    const float* bfc   = (const float*)d_in[11];
    float* out = (float*)d_out;

    char* ws = (char*)d_ws;
    float* tmp   = (float*)ws;  ws += (size_t)NUM_EMBED * HID * 4;          // 6.9 MB
    float* feat1 = (float*)ws;  ws += (size_t)N_NODES * HID * 4;            // 8 MB (reused as agg2)
    float* agg1  = (float*)ws;  ws += (size_t)N_NODES * HID * 4;            // 8 MB
    float* M1    = (float*)ws;  ws += 32 * 256 * 4;
    float* M2    = (float*)ws;  ws += 32 * 256 * 4;
    float* bias  = (float*)ws;  ws += 256 * 4;
    int*   cnt   = (int*)ws;    ws += (size_t)NGROUP * NBUCK * 4;           // 32 KB
    int*   bins  = (int*)ws;    ws += (size_t)NGROUP * NBUCK * CAP * 4;     // 8 MB
    float* agg2  = feat1;   // feat1 dead after spmm1; reuse as agg2

    hipMemsetAsync(cnt, 0, (size_t)NGROUP * NBUCK * sizeof(int), stream);

    k_bin<<<2048, 256, 0, stream>>>(src, dst, cnt, bins);
    k_embed_w1<<<(NUM_EMBED + 127) / 128, 256, 0, stream>>>(embed, W1, tmp);
    k_fold<<<65, 256, 0, stream>>>(W2, b2, Wfc, bfc, M1, M2, bias);
    k_gather<<<(N_NODES * 8) / 256, 256, 0, stream>>>(tmp, idx, feat1);

    k_spmm_binned<1><<<NBUCK, 256, 0, stream>>>(feat1, cnt, bins, b1, agg1);
    k_spmm_binned<0><<<NBUCK, 256, 0, stream>>>(agg1, cnt, bins, b1, agg2);

    k_final<<<BATCH, 256, 0, stream>>>(agg2, g1, g2, M1, M2, bias, out);
}

// Round 4
// 219.486 us; speedup vs baseline: 2.2300x; 2.2300x over previous
//
#include <hip/hip_runtime.h>

#define IN_FEATS 256
#define HID 32
#define OUT_FEATS 256
#define NUM_EMBED 54012
#define N_NODES 65536
#define N_EDGES 1048576
#define BATCH 4096

#define NG 8            // XCD groups
#define CAP 8           // slots per (group,node) cell; degree/node ~Poisson(16) -> ~Poisson(2)/cell
#define OVF_CAP 65536   // overflow list capacity (expected ~600 entries)

// ---------------------------------------------------------------------------
// K1: tmp[r][c] = sum_k embed[r][k] * W1[k][c]   (54012 x 32)
// ---------------------------------------------------------------------------
__global__ void k_embed_w1(const float* __restrict__ embed,
                           const float* __restrict__ W1,
                           float* __restrict__ tmp) {
    __shared__ float w1s[IN_FEATS * HID];
    int tid = threadIdx.x;
    for (int i = tid; i < IN_FEATS * HID / 4; i += 256)
        ((float4*)w1s)[i] = ((const float4*)W1)[i];
    __syncthreads();

    int rg = tid >> 3;
    int cg = tid & 7;
    int r0 = blockIdx.x * 128 + rg * 4;
    int c0 = cg * 4;

    int ra = min(r0 + 0, NUM_EMBED - 1);
    int rb = min(r0 + 1, NUM_EMBED - 1);
    int rc = min(r0 + 2, NUM_EMBED - 1);
    int rd = min(r0 + 3, NUM_EMBED - 1);
    const float4* E0 = (const float4*)(embed + (size_t)ra * IN_FEATS);
    const float4* E1 = (const float4*)(embed + (size_t)rb * IN_FEATS);
    const float4* E2 = (const float4*)(embed + (size_t)rc * IN_FEATS);
    const float4* E3 = (const float4*)(embed + (size_t)rd * IN_FEATS);

    float4 a0 = {0,0,0,0}, a1 = {0,0,0,0}, a2 = {0,0,0,0}, a3 = {0,0,0,0};

#define FMA4(ACC, S, W) \
    ACC.x += (S) * (W).x; ACC.y += (S) * (W).y; ACC.z += (S) * (W).z; ACC.w += (S) * (W).w;

    for (int k4 = 0; k4 < IN_FEATS / 4; ++k4) {
        float4 e0 = E0[k4], e1 = E1[k4], e2 = E2[k4], e3 = E3[k4];
        const float4* wr = (const float4*)(w1s + (k4 * 4) * HID) + cg;
        float4 w;
        w = wr[0];  FMA4(a0, e0.x, w) FMA4(a1, e1.x, w) FMA4(a2, e2.x, w) FMA4(a3, e3.x, w)
        w = wr[8];  FMA4(a0, e0.y, w) FMA4(a1, e1.y, w) FMA4(a2, e2.y, w) FMA4(a3, e3.y, w)
        w = wr[16]; FMA4(a0, e0.z, w) FMA4(a1, e1.z, w) FMA4(a2, e2.z, w) FMA4(a3, e3.z, w)
        w = wr[24]; FMA4(a0, e0.w, w) FMA4(a1, e1.w, w) FMA4(a2, e2.w, w) FMA4(a3, e3.w, w)
    }
#undef FMA4

    if (r0 + 0 < NUM_EMBED) *(float4*)(tmp + (size_t)(r0 + 0) * HID + c0) = a0;
    if (r0 + 1 < NUM_EMBED) *(float4*)(tmp + (size_t)(r0 + 1) * HID + c0) = a1;
    if (r0 + 2 < NUM_EMBED) *(float4*)(tmp + (size_t)(r0 + 2) * HID + c0) = a2;
    if (r0 + 3 < NUM_EMBED) *(float4*)(tmp + (size_t)(r0 + 3) * HID + c0) = a3;
}

// ---------------------------------------------------------------------------
// K2: feat1[n][:] = tmp[idx[n]][:]
// ---------------------------------------------------------------------------
__global__ void k_gather(const float* __restrict__ tmp,
                         const int* __restrict__ idx,
                         float* __restrict__ feat1) {
    int t = blockIdx.x * 256 + threadIdx.x;
    int n = t >> 3;
    int c = (t & 7) * 4;
    if (n >= N_NODES) return;
    int e = idx[n];
    float4 v = *(const float4*)(tmp + (size_t)e * HID + c);
    *(float4*)(feat1 + (size_t)n * HID + c) = v;
}

// ---------------------------------------------------------------------------
// K_bin: fused count+fill. One int atomic per edge. Group g = blockIdx&7
// keeps each group's bins region XCD-local (L2 write combining).
// bins[g][node][CAP] holds src ids; overflow -> global list (rare, ~600).
// ---------------------------------------------------------------------------
__global__ void k_bin(const int* __restrict__ src, const int* __restrict__ dst,
                      int* __restrict__ cnt, int* __restrict__ bins,
                      int* __restrict__ ovf_cnt, int* __restrict__ ovf) {
    int g = blockIdx.x & (NG - 1);
    int t = blockIdx.x * 256 + threadIdx.x;
    for (int e = t; e < N_EDGES; e += 2048 * 256) {
        int s = src[e], d = dst[e];
        int pos = atomicAdd(&cnt[(g << 16) + d], 1);
        if (pos < CAP) {
            bins[((size_t)((g << 16) + d) << 3) + pos] = s;
        } else {
            int o = atomicAdd(ovf_cnt, 1);
            if (o < OVF_CAP) ovf[o] = (int)((unsigned)s | ((unsigned)d << 16));
        }
    }
}

// ---------------------------------------------------------------------------
// K_ovf: apply overflow edges: aggdst[d][c] += featsrc[s][c]  (f32 atomics,
// only ~600 edges). Runs BEFORE the corresponding spmm which then adds the
// pre-accumulated value.
// ---------------------------------------------------------------------------
__global__ void k_ovf(const float* __restrict__ featsrc,
                      const int* __restrict__ ovf_cnt, const int* __restrict__ ovf,
                      float* __restrict__ aggdst) {
    int total = min(*ovf_cnt, OVF_CAP);
    int t = blockIdx.x * 256 + threadIdx.x;
    int c = t & 31;
    for (int i = t >> 5; i < total; i += (64 * 256) >> 5) {
        int p = ovf[i];
        int s = p & 0xFFFF;
        int d = (p >> 16) & 0xFFFF;
        atomicAdd(&aggdst[((size_t)d << 5) + c], featsrc[((size_t)s << 5) + c]);
    }
}

// ---------------------------------------------------------------------------
// SpMM1: agg1[v][c] = relu(agg1[v][c] + sum_edges feat1[s][c] + b1[c])
// 32 lanes per node; 8 independent cnt loads + 2 int4 cell loads per group;
// up to 16 independent feat-row reads -> deep MLP, no dependent chains.
// ---------------------------------------------------------------------------
__global__ void k_spmm1(const float* __restrict__ feat1,
                        const int* __restrict__ cnt, const int* __restrict__ bins,
                        const float* __restrict__ b1, float* __restrict__ agg1) {
    int t = blockIdx.x * 256 + threadIdx.x;
    int v = t >> 5, c = t & 31;
    int n[NG];
#pragma unroll
    for (int g = 0; g < NG; ++g) n[g] = min(cnt[(g << 16) + v], CAP);
    float acc = 0.f;
#pragma unroll
    for (int g = 0; g < NG; ++g) {
        const int4* cell = (const int4*)(bins + ((size_t)((g << 16) + v) << 3));
        int4 lo = cell[0], hi = cell[1];
        int m = n[g];
        if (m > 0) acc += feat1[((size_t)lo.x << 5) + c];
        if (m > 1) acc += feat1[((size_t)lo.y << 5) + c];
        if (m > 2) acc += feat1[((size_t)lo.z << 5) + c];
        if (m > 3) acc += feat1[((size_t)lo.w << 5) + c];
        if (m > 4) acc += feat1[((size_t)hi.x << 5) + c];
        if (m > 5) acc += feat1[((size_t)hi.y << 5) + c];
        if (m > 6) acc += feat1[((size_t)hi.z << 5) + c];
        if (m > 7) acc += feat1[((size_t)hi.w << 5) + c];
    }
    agg1[t] = fmaxf(agg1[t] + acc + b1[c], 0.f);
}

// ---------------------------------------------------------------------------
// SpMM2 over only the 8192 batch slots: pairfeat[slot][c] =
//   agg2ov[v][c] + sum_edges agg1[s][c],  v = g1/g2[slot]
// ---------------------------------------------------------------------------
__global__ void k_spmm2b(const float* __restrict__ agg1,
                         const int* __restrict__ cnt, const int* __restrict__ bins,
                         const int* __restrict__ g1, const int* __restrict__ g2,
                         const float* __restrict__ agg2ov,
                         float* __restrict__ pairfeat) {
    int t = blockIdx.x * 256 + threadIdx.x;
    int slot = t >> 5, c = t & 31;
    int v = (slot < BATCH) ? g1[slot] : g2[slot - BATCH];
    int n[NG];
#pragma unroll
    for (int g = 0; g < NG; ++g) n[g] = min(cnt[(g << 16) + v], CAP);
    float acc = agg2ov[((size_t)v << 5) + c];
#pragma unroll
    for (int g = 0; g < NG; ++g) {
        const int4* cell = (const int4*)(bins + ((size_t)((g << 16) + v) << 3));
        int4 lo = cell[0], hi = cell[1];
        int m = n[g];
        if (m > 0) acc += agg1[((size_t)lo.x << 5) + c];
        if (m > 1) acc += agg1[((size_t)lo.y << 5) + c];
        if (m > 2) acc += agg1[((size_t)lo.z << 5) + c];
        if (m > 3) acc += agg1[((size_t)lo.w << 5) + c];
        if (m > 4) acc += agg1[((size_t)hi.x << 5) + c];
        if (m > 5) acc += agg1[((size_t)hi.y << 5) + c];
        if (m > 6) acc += agg1[((size_t)hi.z << 5) + c];
        if (m > 7) acc += agg1[((size_t)hi.w << 5) + c];
    }
    pairfeat[t] = acc;
}

// ---------------------------------------------------------------------------
// K6: fold W2/Wfc/b2/bfc into M1[32,256], M2[32,256], bias[256]
// ---------------------------------------------------------------------------
__global__ void k_fold(const float* __restrict__ W2, const float* __restrict__ b2,
                       const float* __restrict__ Wfc, const float* __restrict__ bfc,
                       float* __restrict__ M1, float* __restrict__ M2,
                       float* __restrict__ bias) {
    int c = threadIdx.x;
    int r = blockIdx.x;
    if (r < 32) {
        float acc = 0.f;
        for (int j = 0; j < 256; ++j) acc += W2[r * 256 + j] * Wfc[j * 256 + c];
        M1[r * 256 + c] = acc;
    } else if (r < 64) {
        int k = r - 32;
        float acc = 0.f;
        for (int j = 0; j < 256; ++j) acc += W2[k * 256 + j] * Wfc[(256 + j) * 256 + c];
        M2[k * 256 + c] = acc;
    } else {
        float acc = bfc[c];
        for (int j = 0; j < 256; ++j) acc += b2[j] * (Wfc[j * 256 + c] + Wfc[(256 + j) * 256 + c]);
        bias[c] = acc;
    }
}

// ---------------------------------------------------------------------------
// K7: out[i][c] = relu(pairfeat[i] @ M1[:,c] + pairfeat[B+i] @ M2[:,c] + bias[c])
// ---------------------------------------------------------------------------
__global__ void k_final(const float* __restrict__ pairfeat,
                        const float* __restrict__ M1, const float* __restrict__ M2,
                        const float* __restrict__ bias,
                        float* __restrict__ out) {
    __shared__ float a1s[HID];
    __shared__ float a2s[HID];
    int i = blockIdx.x;
    int c = threadIdx.x;
    if (c < 32) a1s[c] = pairfeat[(size_t)i * HID + c];
    else if (c < 64) a2s[c - 32] = pairfeat[(size_t)(BATCH + i) * HID + (c - 32)];
    __syncthreads();

    float acc = bias[c];
#pragma unroll
    for (int k = 0; k < HID; ++k) {
        acc += a1s[k] * M1[k * 256 + c];
        acc += a2s[k] * M2[k * 256 + c];
    }
    out[(size_t)i * 256 + c] = fmaxf(acc, 0.f);
}

// ---------------------------------------------------------------------------
extern "C" void kernel_launch(void* const* d_in, const int* in_sizes, int n_in,
                              void* d_out, int out_size, void* d_ws, size_t ws_size,
                              hipStream_t stream) {
    const int*   idx   = (const int*)d_in[0];
    const int*   src   = (const int*)d_in[1];
    const int*   dst   = (const int*)d_in[2];
    const int*   g1    = (const int*)d_in[3];
    const int*   g2    = (const int*)d_in[4];
    const float* embed = (const float*)d_in[5];
    const float* W1    = (const float*)d_in[6];
    const float* b1    = (const float*)d_in[7];
    const float* W2    = (const float*)d_in[8];
    const float* b2    = (const float*)d_in[9];
    const float* Wfc   = (const float*)d_in[10];
    const float* bfc   = (const float*)d_in[11];
    float* out = (float*)d_out;

    char* ws = (char*)d_ws;
    float* tmp      = (float*)ws;  ws += (size_t)NUM_EMBED * HID * 4;        // 6.9 MB
    float* feat1    = (float*)ws;  ws += (size_t)N_NODES * HID * 4;          // 8 MB
    float* agg1     = (float*)ws;  ws += (size_t)N_NODES * HID * 4;          // 8 MB
    float* agg2ov   = (float*)ws;  ws += (size_t)N_NODES * HID * 4;          // 8 MB
    float* pairfeat = (float*)ws;  ws += (size_t)2 * BATCH * HID * 4;        // 1 MB
    float* M1       = (float*)ws;  ws += 32 * 256 * 4;
    float* M2       = (float*)ws;  ws += 32 * 256 * 4;
    float* bias     = (float*)ws;  ws += 256 * 4;
    int*   cnt      = (int*)ws;    ws += (size_t)NG * N_NODES * 4;           // 2 MB
    int*   bins     = (int*)ws;    ws += (size_t)NG * N_NODES * CAP * 4;     // 16 MB
    int*   ovf_cnt  = (int*)ws;    ws += 256;
    int*   ovf      = (int*)ws;    ws += (size_t)OVF_CAP * 4;                // 256 KB

    hipMemsetAsync(cnt, 0, (size_t)NG * N_NODES * sizeof(int), stream);
    hipMemsetAsync(ovf_cnt, 0, sizeof(int), stream);
    hipMemsetAsync(agg1, 0, (size_t)N_NODES * HID * sizeof(float), stream);
    hipMemsetAsync(agg2ov, 0, (size_t)N_NODES * HID * sizeof(float), stream);

    k_bin<<<2048, 256, 0, stream>>>(src, dst, cnt, bins, ovf_cnt, ovf);
    k_embed_w1<<<(NUM_EMBED + 127) / 128, 256, 0, stream>>>(embed, W1, tmp);
    k_fold<<<65, 256, 0, stream>>>(W2, b2, Wfc, bfc, M1, M2, bias);
    k_gather<<<(N_NODES * 8) / 256, 256, 0, stream>>>(tmp, idx, feat1);

    k_ovf<<<64, 256, 0, stream>>>(feat1, ovf_cnt, ovf, agg1);
    k_spmm1<<<(N_NODES * 32) / 256, 256, 0, stream>>>(feat1, cnt, bins, b1, agg1);
    k_ovf<<<64, 256, 0, stream>>>(agg1, ovf_cnt, ovf, agg2ov);
    k_spmm2b<<<(2 * BATCH * 32) / 256, 256, 0, stream>>>(agg1, cnt, bins, g1, g2, agg2ov, pairfeat);

    k_final<<<BATCH, 256, 0, stream>>>(pairfeat, M1, M2, bias, out);
}

// Round 5
// 207.760 us; speedup vs baseline: 2.3558x; 1.0564x over previous
//
#include <hip/hip_runtime.h>

#define IN_FEATS 256
#define HID 32
#define OUT_FEATS 256
#define NUM_EMBED 54012
#define N_NODES 65536
#define N_EDGES 1048576
#define BATCH 4096

#define NG 8            // XCD groups (blockIdx & 7 ~ XCD id)
#define CAP 8           // u16 slots per (group,node) cell = one 16B int4
#define OVF_CAP 65536   // overflow list capacity (expected ~150 entries)

// ---------------------------------------------------------------------------
// K1: tmp[r][c] = sum_k embed[r][k] * W1[k][c]   (54012 x 32)
// ---------------------------------------------------------------------------
__global__ void k_embed_w1(const float* __restrict__ embed,
                           const float* __restrict__ W1,
                           float* __restrict__ tmp) {
    __shared__ float w1s[IN_FEATS * HID];
    int tid = threadIdx.x;
    for (int i = tid; i < IN_FEATS * HID / 4; i += 256)
        ((float4*)w1s)[i] = ((const float4*)W1)[i];
    __syncthreads();

    int rg = tid >> 3;
    int cg = tid & 7;
    int r0 = blockIdx.x * 128 + rg * 4;
    int c0 = cg * 4;

    int ra = min(r0 + 0, NUM_EMBED - 1);
    int rb = min(r0 + 1, NUM_EMBED - 1);
    int rc = min(r0 + 2, NUM_EMBED - 1);
    int rd = min(r0 + 3, NUM_EMBED - 1);
    const float4* E0 = (const float4*)(embed + (size_t)ra * IN_FEATS);
    const float4* E1 = (const float4*)(embed + (size_t)rb * IN_FEATS);
    const float4* E2 = (const float4*)(embed + (size_t)rc * IN_FEATS);
    const float4* E3 = (const float4*)(embed + (size_t)rd * IN_FEATS);

    float4 a0 = {0,0,0,0}, a1 = {0,0,0,0}, a2 = {0,0,0,0}, a3 = {0,0,0,0};

#define FMA4(ACC, S, W) \
    ACC.x += (S) * (W).x; ACC.y += (S) * (W).y; ACC.z += (S) * (W).z; ACC.w += (S) * (W).w;

    for (int k4 = 0; k4 < IN_FEATS / 4; ++k4) {
        float4 e0 = E0[k4], e1 = E1[k4], e2 = E2[k4], e3 = E3[k4];
        const float4* wr = (const float4*)(w1s + (k4 * 4) * HID) + cg;
        float4 w;
        w = wr[0];  FMA4(a0, e0.x, w) FMA4(a1, e1.x, w) FMA4(a2, e2.x, w) FMA4(a3, e3.x, w)
        w = wr[8];  FMA4(a0, e0.y, w) FMA4(a1, e1.y, w) FMA4(a2, e2.y, w) FMA4(a3, e3.y, w)
        w = wr[16]; FMA4(a0, e0.z, w) FMA4(a1, e1.z, w) FMA4(a2, e2.z, w) FMA4(a3, e3.z, w)
        w = wr[24]; FMA4(a0, e0.w, w) FMA4(a1, e1.w, w) FMA4(a2, e2.w, w) FMA4(a3, e3.w, w)
    }
#undef FMA4

    if (r0 + 0 < NUM_EMBED) *(float4*)(tmp + (size_t)(r0 + 0) * HID + c0) = a0;
    if (r0 + 1 < NUM_EMBED) *(float4*)(tmp + (size_t)(r0 + 1) * HID + c0) = a1;
    if (r0 + 2 < NUM_EMBED) *(float4*)(tmp + (size_t)(r0 + 2) * HID + c0) = a2;
    if (r0 + 3 < NUM_EMBED) *(float4*)(tmp + (size_t)(r0 + 3) * HID + c0) = a3;
}

// ---------------------------------------------------------------------------
// K_bin: fused count+fill, u16 entries. One int atomic + one 2B store per
// edge. nontemporal src/dst reads keep the bins/cnt working set L2-resident.
// ---------------------------------------------------------------------------
__global__ void k_bin(const int* __restrict__ src, const int* __restrict__ dst,
                      int* __restrict__ cnt, unsigned short* __restrict__ bins,
                      int* __restrict__ ovf_cnt, int* __restrict__ ovf) {
    int g = blockIdx.x & (NG - 1);
    int t = blockIdx.x * 256 + threadIdx.x;
    for (int e = t; e < N_EDGES; e += 2048 * 256) {
        int s = __builtin_nontemporal_load(&src[e]);
        int d = __builtin_nontemporal_load(&dst[e]);
        int gi = (g << 16) + d;
        int pos = atomicAdd(&cnt[gi], 1);
        if (pos < CAP) {
            bins[((size_t)gi << 3) + pos] = (unsigned short)s;
        } else {
            int o = atomicAdd(ovf_cnt, 1);
            if (o < OVF_CAP) ovf[o] = (int)((unsigned)s | ((unsigned)d << 16));
        }
    }
}

// ---------------------------------------------------------------------------
// Overflow pre-accumulation (rare, ~150 edges): f32 atomics.
// ---------------------------------------------------------------------------
__global__ void k_ovf1(const float* __restrict__ tmp, const int* __restrict__ idx,
                       const int* __restrict__ ovf_cnt, const int* __restrict__ ovf,
                       float* __restrict__ agg1) {
    int total = min(*ovf_cnt, OVF_CAP);
    int t = blockIdx.x * 256 + threadIdx.x;
    int c = t & 31;
    for (int i = t >> 5; i < total; i += 512) {
        unsigned p = (unsigned)ovf[i];
        int s = p & 0xFFFFu;
        int d = p >> 16;
        atomicAdd(&agg1[((size_t)d << 5) + c], tmp[((size_t)idx[s] << 5) + c]);
    }
}

__global__ void k_ovf2(const float* __restrict__ agg1,
                       const int* __restrict__ ovf_cnt, const int* __restrict__ ovf,
                       float* __restrict__ agg2ov) {
    int total = min(*ovf_cnt, OVF_CAP);
    int t = blockIdx.x * 256 + threadIdx.x;
    int c = t & 31;
    for (int i = t >> 5; i < total; i += 512) {
        unsigned p = (unsigned)ovf[i];
        int s = p & 0xFFFFu;
        int d = p >> 16;
        atomicAdd(&agg2ov[((size_t)d << 5) + c], agg1[((size_t)s << 5) + c]);
    }
}

// ---------------------------------------------------------------------------
// SpMM1 (fused embedding gather):
// agg1[v][c] = relu(agg1[v][c](=ovf) + sum_edges tmp[idx[s]][c] + b1[c])
// 32 lanes/node; 8 cnt + 8 int4 cell loads upfront, <=16 row reads, 2 acc.
// ---------------------------------------------------------------------------
__global__ void k_spmm1(const float* __restrict__ tmp, const int* __restrict__ idx,
                        const int* __restrict__ cnt,
                        const unsigned short* __restrict__ bins,
                        const float* __restrict__ b1, float* __restrict__ agg1) {
    int t = blockIdx.x * 256 + threadIdx.x;
    int v = t >> 5, c = t & 31;
    int n[NG];
    int4 cl[NG];
#pragma unroll
    for (int g = 0; g < NG; ++g) {
        n[g] = min(cnt[(g << 16) + v], CAP);
        cl[g] = ((const int4*)bins)[(g << 16) + v];
    }
    float acc0 = 0.f, acc1 = 0.f;
#pragma unroll
    for (int g = 0; g < NG; ++g) {
        int m = n[g];
        unsigned qa = (unsigned)cl[g].x, qb = (unsigned)cl[g].y;
        unsigned qc = (unsigned)cl[g].z, qd = (unsigned)cl[g].w;
        if (m > 0) acc0 += tmp[((size_t)idx[qa & 0xFFFFu] << 5) + c];
        if (m > 1) acc1 += tmp[((size_t)idx[qa >> 16] << 5) + c];
        if (m > 2) acc0 += tmp[((size_t)idx[qb & 0xFFFFu] << 5) + c];
        if (m > 3) acc1 += tmp[((size_t)idx[qb >> 16] << 5) + c];
        if (m > 4) acc0 += tmp[((size_t)idx[qc & 0xFFFFu] << 5) + c];
        if (m > 5) acc1 += tmp[((size_t)idx[qc >> 16] << 5) + c];
        if (m > 6) acc0 += tmp[((size_t)idx[qd & 0xFFFFu] << 5) + c];
        if (m > 7) acc1 += tmp[((size_t)idx[qd >> 16] << 5) + c];
    }
    agg1[t] = fmaxf(agg1[t] + acc0 + acc1 + b1[c], 0.f);
}

// ---------------------------------------------------------------------------
// SpMM2 over the 8192 batch slots only.
// ---------------------------------------------------------------------------
__global__ void k_spmm2b(const float* __restrict__ agg1,
                         const int* __restrict__ cnt,
                         const unsigned short* __restrict__ bins,
                         const int* __restrict__ g1, const int* __restrict__ g2,
                         const float* __restrict__ agg2ov,
                         float* __restrict__ pairfeat) {
    int t = blockIdx.x * 256 + threadIdx.x;
    int slot = t >> 5, c = t & 31;
    int v = (slot < BATCH) ? g1[slot] : g2[slot - BATCH];
    int n[NG];
    int4 cl[NG];
#pragma unroll
    for (int g = 0; g < NG; ++g) {
        n[g] = min(cnt[(g << 16) + v], CAP);
        cl[g] = ((const int4*)bins)[(g << 16) + v];
    }
    float acc0 = agg2ov[((size_t)v << 5) + c], acc1 = 0.f;
#pragma unroll
    for (int g = 0; g < NG; ++g) {
        int m = n[g];
        unsigned qa = (unsigned)cl[g].x, qb = (unsigned)cl[g].y;
        unsigned qc = (unsigned)cl[g].z, qd = (unsigned)cl[g].w;
        if (m > 0) acc0 += agg1[((size_t)(qa & 0xFFFFu) << 5) + c];
        if (m > 1) acc1 += agg1[((size_t)(qa >> 16) << 5) + c];
        if (m > 2) acc0 += agg1[((size_t)(qb & 0xFFFFu) << 5) + c];
        if (m > 3) acc1 += agg1[((size_t)(qb >> 16) << 5) + c];
        if (m > 4) acc0 += agg1[((size_t)(qc & 0xFFFFu) << 5) + c];
        if (m > 5) acc1 += agg1[((size_t)(qc >> 16) << 5) + c];
        if (m > 6) acc0 += agg1[((size_t)(qd & 0xFFFFu) << 5) + c];
        if (m > 7) acc1 += agg1[((size_t)(qd >> 16) << 5) + c];
    }
    pairfeat[t] = acc0 + acc1;
}

// ---------------------------------------------------------------------------
// K6: fold W2/Wfc/b2/bfc into M1[32,256], M2[32,256], bias[256]
// ---------------------------------------------------------------------------
__global__ void k_fold(const float* __restrict__ W2, const float* __restrict__ b2,
                       const float* __restrict__ Wfc, const float* __restrict__ bfc,
                       float* __restrict__ M1, float* __restrict__ M2,
                       float* __restrict__ bias) {
    int c = threadIdx.x;
    int r = blockIdx.x;
    if (r < 32) {
        float acc = 0.f;
        for (int j = 0; j < 256; ++j) acc += W2[r * 256 + j] * Wfc[j * 256 + c];
        M1[r * 256 + c] = acc;
    } else if (r < 64) {
        int k = r - 32;
        float acc = 0.f;
        for (int j = 0; j < 256; ++j) acc += W2[k * 256 + j] * Wfc[(256 + j) * 256 + c];
        M2[k * 256 + c] = acc;
    } else {
        float acc = bfc[c];
        for (int j = 0; j < 256; ++j) acc += b2[j] * (Wfc[j * 256 + c] + Wfc[(256 + j) * 256 + c]);
        bias[c] = acc;
    }
}

// ---------------------------------------------------------------------------
// K7: 4 pairs per block; M1/M2 rows shared in registers across the 4 pairs.
// out[i][c] = relu(pairfeat[i] @ M1[:,c] + pairfeat[B+i] @ M2[:,c] + bias[c])
// ---------------------------------------------------------------------------
__global__ void k_final(const float* __restrict__ pairfeat,
                        const float* __restrict__ M1, const float* __restrict__ M2,
                        const float* __restrict__ bias,
                        float* __restrict__ out) {
    __shared__ float a1s[4][HID];
    __shared__ float a2s[4][HID];
    int i0 = blockIdx.x * 4;
    int tid = threadIdx.x;
    {
        int p = tid >> 6;
        int w = tid & 63;
        if (w < 32) a1s[p][w] = pairfeat[(size_t)(i0 + p) * HID + w];
        else        a2s[p][w - 32] = pairfeat[(size_t)(BATCH + i0 + p) * HID + (w - 32)];
    }
    __syncthreads();

    int c = tid;
    float acc0 = bias[c], acc1 = bias[c], acc2 = bias[c], acc3 = bias[c];
#pragma unroll
    for (int k = 0; k < HID; ++k) {
        float m1 = M1[k * 256 + c];
        float m2 = M2[k * 256 + c];
        acc0 += a1s[0][k] * m1 + a2s[0][k] * m2;
        acc1 += a1s[1][k] * m1 + a2s[1][k] * m2;
        acc2 += a1s[2][k] * m1 + a2s[2][k] * m2;
        acc3 += a1s[3][k] * m1 + a2s[3][k] * m2;
    }
    out[(size_t)(i0 + 0) * 256 + c] = fmaxf(acc0, 0.f);
    out[(size_t)(i0 + 1) * 256 + c] = fmaxf(acc1, 0.f);
    out[(size_t)(i0 + 2) * 256 + c] = fmaxf(acc2, 0.f);
    out[(size_t)(i0 + 3) * 256 + c] = fmaxf(acc3, 0.f);
}

// ---------------------------------------------------------------------------
extern "C" void kernel_launch(void* const* d_in, const int* in_sizes, int n_in,
                              void* d_out, int out_size, void* d_ws, size_t ws_size,
                              hipStream_t stream) {
    const int*   idx   = (const int*)d_in[0];
    const int*   src   = (const int*)d_in[1];
    const int*   dst   = (const int*)d_in[2];
    const int*   g1    = (const int*)d_in[3];
    const int*   g2    = (const int*)d_in[4];
    const float* embed = (const float*)d_in[5];
    const float* W1    = (const float*)d_in[6];
    const float* b1    = (const float*)d_in[7];
    const float* W2    = (const float*)d_in[8];
    const float* b2    = (const float*)d_in[9];
    const float* Wfc   = (const float*)d_in[10];
    const float* bfc   = (const float*)d_in[11];
    float* out = (float*)d_out;

    char* ws = (char*)d_ws;
    float* tmp      = (float*)ws;  ws += (size_t)NUM_EMBED * HID * 4;        // 6.9 MB
    float* agg1     = (float*)ws;  ws += (size_t)N_NODES * HID * 4;          // 8 MB  } one memset
    float* agg2ov   = (float*)ws;  ws += (size_t)N_NODES * HID * 4;          // 8 MB  }
    float* pairfeat = (float*)ws;  ws += (size_t)2 * BATCH * HID * 4;        // 1 MB
    float* M1       = (float*)ws;  ws += 32 * 256 * 4;
    float* M2       = (float*)ws;  ws += 32 * 256 * 4;
    float* bias     = (float*)ws;  ws += 256 * 4;
    int*   cnt      = (int*)ws;    ws += (size_t)NG * N_NODES * 4;           // 2 MB  } one memset
    int*   ovf_cnt  = (int*)ws;    ws += 64;                                 //       }
    unsigned short* bins = (unsigned short*)ws;
                                   ws += (size_t)NG * N_NODES * CAP * 2;     // 8 MB
    int*   ovf      = (int*)ws;    ws += (size_t)OVF_CAP * 4;                // 256 KB

    hipMemsetAsync(cnt, 0, (size_t)NG * N_NODES * 4 + 64, stream);
    hipMemsetAsync(agg1, 0, (size_t)2 * N_NODES * HID * sizeof(float), stream);

    k_bin<<<2048, 256, 0, stream>>>(src, dst, cnt, bins, ovf_cnt, ovf);
    k_embed_w1<<<(NUM_EMBED + 127) / 128, 256, 0, stream>>>(embed, W1, tmp);
    k_fold<<<65, 256, 0, stream>>>(W2, b2, Wfc, bfc, M1, M2, bias);

    k_ovf1<<<64, 256, 0, stream>>>(tmp, idx, ovf_cnt, ovf, agg1);
    k_spmm1<<<(N_NODES * 32) / 256, 256, 0, stream>>>(tmp, idx, cnt, bins, b1, agg1);
    k_ovf2<<<64, 256, 0, stream>>>(agg1, ovf_cnt, ovf, agg2ov);
    k_spmm2b<<<(2 * BATCH * 32) / 256, 256, 0, stream>>>(agg1, cnt, bins, g1, g2, agg2ov, pairfeat);

    k_final<<<BATCH / 4, 256, 0, stream>>>(pairfeat, M1, M2, bias, out);
}

// Round 6
// 147.615 us; speedup vs baseline: 3.3157x; 1.4074x over previous
//
#include <hip/hip_runtime.h>

#define IN_FEATS 256
#define HID 32
#define NUM_EMBED 54012
#define N_NODES 65536
#define N_EDGES 1048576
#define BATCH 4096

#define NG 8            // XCD groups (blockIdx & 7 ~ XCD id)
#define CAP 8           // u16 slots per (group,node) cell = one 16B int4
#define OVF_CAP 65536   // overflow list capacity (expected ~150 entries)

typedef unsigned short u16t;
typedef unsigned int u32t;

__device__ __forceinline__ float bf2f(u16t u) {
    return __uint_as_float(((u32t)u) << 16);
}
__device__ __forceinline__ u16t f2bf(float f) {
    u32t x = __float_as_uint(f);
    return (u16t)((x + 0x7FFFu + ((x >> 16) & 1u)) >> 16);   // RNE
}

// ---------------------------------------------------------------------------
// K1: tmpb[r][c] = bf16( sum_k embed[r][k] * W1[k][c] )   (54012 x 32)
// ---------------------------------------------------------------------------
__global__ void k_embed_w1(const float* __restrict__ embed,
                           const float* __restrict__ W1,
                           u16t* __restrict__ tmpb) {
    __shared__ float w1s[IN_FEATS * HID];
    int tid = threadIdx.x;
    for (int i = tid; i < IN_FEATS * HID / 4; i += 256)
        ((float4*)w1s)[i] = ((const float4*)W1)[i];
    __syncthreads();

    int rg = tid >> 3;
    int cg = tid & 7;
    int r0 = blockIdx.x * 128 + rg * 4;
    int c0 = cg * 4;

    int ra = min(r0 + 0, NUM_EMBED - 1);
    int rb = min(r0 + 1, NUM_EMBED - 1);
    int rc = min(r0 + 2, NUM_EMBED - 1);
    int rd = min(r0 + 3, NUM_EMBED - 1);
    const float4* E0 = (const float4*)(embed + (size_t)ra * IN_FEATS);
    const float4* E1 = (const float4*)(embed + (size_t)rb * IN_FEATS);
    const float4* E2 = (const float4*)(embed + (size_t)rc * IN_FEATS);
    const float4* E3 = (const float4*)(embed + (size_t)rd * IN_FEATS);

    float4 a0 = {0,0,0,0}, a1 = {0,0,0,0}, a2 = {0,0,0,0}, a3 = {0,0,0,0};

#define FMA4(ACC, S, W) \
    ACC.x += (S) * (W).x; ACC.y += (S) * (W).y; ACC.z += (S) * (W).z; ACC.w += (S) * (W).w;

    for (int k4 = 0; k4 < IN_FEATS / 4; ++k4) {
        float4 e0 = E0[k4], e1 = E1[k4], e2 = E2[k4], e3 = E3[k4];
        const float4* wr = (const float4*)(w1s + (k4 * 4) * HID) + cg;
        float4 w;
        w = wr[0];  FMA4(a0, e0.x, w) FMA4(a1, e1.x, w) FMA4(a2, e2.x, w) FMA4(a3, e3.x, w)
        w = wr[8];  FMA4(a0, e0.y, w) FMA4(a1, e1.y, w) FMA4(a2, e2.y, w) FMA4(a3, e3.y, w)
        w = wr[16]; FMA4(a0, e0.z, w) FMA4(a1, e1.z, w) FMA4(a2, e2.z, w) FMA4(a3, e3.z, w)
        w = wr[24]; FMA4(a0, e0.w, w) FMA4(a1, e1.w, w) FMA4(a2, e2.w, w) FMA4(a3, e3.w, w)
    }
#undef FMA4

#define ST4(R, A) \
    if (R < NUM_EMBED) { \
        ushort4 s4 = make_ushort4(f2bf(A.x), f2bf(A.y), f2bf(A.z), f2bf(A.w)); \
        *(ushort4*)(tmpb + (size_t)(R) * HID + c0) = s4; \
    }
    ST4(r0 + 0, a0)
    ST4(r0 + 1, a1)
    ST4(r0 + 2, a2)
    ST4(r0 + 3, a3)
#undef ST4
}

// ---------------------------------------------------------------------------
// K2: feat1[n][:] = tmpb[idx[n]][:]   (bf16 rows, 64B, 16 u32 lanes per row)
// ---------------------------------------------------------------------------
__global__ void k_gather(const u32t* __restrict__ tmpu,
                         const int* __restrict__ idx,
                         u32t* __restrict__ feat1u) {
    int t = blockIdx.x * 256 + threadIdx.x;
    int n = t >> 4, j = t & 15;
    feat1u[((size_t)n << 4) + j] = tmpu[((size_t)idx[n] << 4) + j];
}

// ---------------------------------------------------------------------------
// K_bin: fused count+fill, u16 entries, 1 edge/thread.
// ---------------------------------------------------------------------------
__global__ void k_bin(const int* __restrict__ src, const int* __restrict__ dst,
                      int* __restrict__ cnt, u16t* __restrict__ bins,
                      int* __restrict__ ovf_cnt, int* __restrict__ ovf) {
    int g = blockIdx.x & (NG - 1);
    int e = blockIdx.x * 256 + threadIdx.x;
    int s = __builtin_nontemporal_load(&src[e]);
    int d = __builtin_nontemporal_load(&dst[e]);
    int gi = (g << 16) + d;
    int pos = atomicAdd(&cnt[gi], 1);
    if (pos < CAP) {
        bins[((size_t)gi << 3) + pos] = (u16t)s;
    } else {
        int o = atomicAdd(ovf_cnt, 1);
        if (o < OVF_CAP) ovf[o] = (int)((unsigned)s | ((unsigned)d << 16));
    }
}

// ---------------------------------------------------------------------------
// Overflow pre-accumulation (rare): f32 atomics.
// ---------------------------------------------------------------------------
__global__ void k_ovf1(const u16t* __restrict__ feat1,
                       const int* __restrict__ ovf_cnt, const int* __restrict__ ovf,
                       float* __restrict__ agg1) {
    int total = min(*ovf_cnt, OVF_CAP);
    int t = blockIdx.x * 256 + threadIdx.x;
    int c = t & 31;
    for (int i = t >> 5; i < total; i += 512) {
        unsigned p = (unsigned)ovf[i];
        int s = p & 0xFFFFu;
        int d = p >> 16;
        atomicAdd(&agg1[((size_t)d << 5) + c], bf2f(feat1[((size_t)s << 5) + c]));
    }
}

__global__ void k_ovf2(const float* __restrict__ agg1,
                       const int* __restrict__ ovf_cnt, const int* __restrict__ ovf,
                       float* __restrict__ agg2ov) {
    int total = min(*ovf_cnt, OVF_CAP);
    int t = blockIdx.x * 256 + threadIdx.x;
    int c = t & 31;
    for (int i = t >> 5; i < total; i += 512) {
        unsigned p = (unsigned)ovf[i];
        int s = p & 0xFFFFu;
        int d = p >> 16;
        atomicAdd(&agg2ov[((size_t)d << 5) + c], agg1[((size_t)s << 5) + c]);
    }
}

// ---------------------------------------------------------------------------
// SpMM1: agg1[v][c] = relu(agg1[v][c](=ovf) + sum_edges feat1[s][c] + b1[c])
// Slots 0..3 of every group loaded UNCONDITIONALLY (any u16 is a valid row;
// weight 0/1 via cndmask) -> 32 independent loads/thread. Tail (m>4, P~5%)
// behind a branch.
// ---------------------------------------------------------------------------
__global__ void k_spmm1(const u16t* __restrict__ feat1,
                        const int* __restrict__ cnt, const u16t* __restrict__ bins,
                        const float* __restrict__ b1, float* __restrict__ agg1) {
    int t = blockIdx.x * 256 + threadIdx.x;
    int v = t >> 5, c = t & 31;
    int m[NG]; int4 cl[NG];
#pragma unroll
    for (int g = 0; g < NG; ++g) {
        m[g] = min(cnt[(g << 16) + v], CAP);
        cl[g] = ((const int4*)bins)[(g << 16) + v];
    }
    float va[NG][4];
#pragma unroll
    for (int g = 0; g < NG; ++g) {
        u32t qa = (u32t)cl[g].x, qb = (u32t)cl[g].y;
        va[g][0] = bf2f(feat1[((size_t)(qa & 0xFFFFu) << 5) + c]);
        va[g][1] = bf2f(feat1[((size_t)(qa >> 16)      << 5) + c]);
        va[g][2] = bf2f(feat1[((size_t)(qb & 0xFFFFu) << 5) + c]);
        va[g][3] = bf2f(feat1[((size_t)(qb >> 16)      << 5) + c]);
    }
    float acc = 0.f;
#pragma unroll
    for (int g = 0; g < NG; ++g) {
        acc += (m[g] > 0) ? va[g][0] : 0.f;
        acc += (m[g] > 1) ? va[g][1] : 0.f;
        acc += (m[g] > 2) ? va[g][2] : 0.f;
        acc += (m[g] > 3) ? va[g][3] : 0.f;
    }
#pragma unroll
    for (int g = 0; g < NG; ++g) {
        if (m[g] > 4) {
            u32t qc = (u32t)cl[g].z, qd = (u32t)cl[g].w;
            float v4 = bf2f(feat1[((size_t)(qc & 0xFFFFu) << 5) + c]);
            float v5 = bf2f(feat1[((size_t)(qc >> 16)      << 5) + c]);
            float v6 = bf2f(feat1[((size_t)(qd & 0xFFFFu) << 5) + c]);
            float v7 = bf2f(feat1[((size_t)(qd >> 16)      << 5) + c]);
            acc += v4;
            acc += (m[g] > 5) ? v5 : 0.f;
            acc += (m[g] > 6) ? v6 : 0.f;
            acc += (m[g] > 7) ? v7 : 0.f;
        }
    }
    agg1[t] = fmaxf(agg1[t] + acc + b1[c], 0.f);
}

// ---------------------------------------------------------------------------
// SpMM2 over the 8192 batch slots only (agg1 is f32, rows 128B).
// ---------------------------------------------------------------------------
__global__ void k_spmm2b(const float* __restrict__ agg1,
                         const int* __restrict__ cnt, const u16t* __restrict__ bins,
                         const int* __restrict__ g1, const int* __restrict__ g2,
                         const float* __restrict__ agg2ov,
                         float* __restrict__ pairfeat) {
    int t = blockIdx.x * 256 + threadIdx.x;
    int slot = t >> 5, c = t & 31;
    int v = (slot < BATCH) ? g1[slot] : g2[slot - BATCH];
    int m[NG]; int4 cl[NG];
#pragma unroll
    for (int g = 0; g < NG; ++g) {
        m[g] = min(cnt[(g << 16) + v], CAP);
        cl[g] = ((const int4*)bins)[(g << 16) + v];
    }
    float va[NG][4];
#pragma unroll
    for (int g = 0; g < NG; ++g) {
        u32t qa = (u32t)cl[g].x, qb = (u32t)cl[g].y;
        va[g][0] = agg1[((size_t)(qa & 0xFFFFu) << 5) + c];
        va[g][1] = agg1[((size_t)(qa >> 16)      << 5) + c];
        va[g][2] = agg1[((size_t)(qb & 0xFFFFu) << 5) + c];
        va[g][3] = agg1[((size_t)(qb >> 16)      << 5) + c];
    }
    float acc = agg2ov[((size_t)v << 5) + c];
#pragma unroll
    for (int g = 0; g < NG; ++g) {
        acc += (m[g] > 0) ? va[g][0] : 0.f;
        acc += (m[g] > 1) ? va[g][1] : 0.f;
        acc += (m[g] > 2) ? va[g][2] : 0.f;
        acc += (m[g] > 3) ? va[g][3] : 0.f;
    }
#pragma unroll
    for (int g = 0; g < NG; ++g) {
        if (m[g] > 4) {
            u32t qc = (u32t)cl[g].z, qd = (u32t)cl[g].w;
            float v4 = agg1[((size_t)(qc & 0xFFFFu) << 5) + c];
            float v5 = agg1[((size_t)(qc >> 16)      << 5) + c];
            float v6 = agg1[((size_t)(qd & 0xFFFFu) << 5) + c];
            float v7 = agg1[((size_t)(qd >> 16)      << 5) + c];
            acc += v4;
            acc += (m[g] > 5) ? v5 : 0.f;
            acc += (m[g] > 6) ? v6 : 0.f;
            acc += (m[g] > 7) ? v7 : 0.f;
        }
    }
    pairfeat[t] = acc;
}

// ---------------------------------------------------------------------------
// K6: fold W2/Wfc/b2/bfc into M1[32,256], M2[32,256], bias[256]
// ---------------------------------------------------------------------------
__global__ void k_fold(const float* __restrict__ W2, const float* __restrict__ b2,
                       const float* __restrict__ Wfc, const float* __restrict__ bfc,
                       float* __restrict__ M1, float* __restrict__ M2,
                       float* __restrict__ bias) {
    int c = threadIdx.x;
    int r = blockIdx.x;
    if (r < 32) {
        float acc = 0.f;
        for (int j = 0; j < 256; ++j) acc += W2[r * 256 + j] * Wfc[j * 256 + c];
        M1[r * 256 + c] = acc;
    } else if (r < 64) {
        int k = r - 32;
        float acc = 0.f;
        for (int j = 0; j < 256; ++j) acc += W2[k * 256 + j] * Wfc[(256 + j) * 256 + c];
        M2[k * 256 + c] = acc;
    } else {
        float acc = bfc[c];
        for (int j = 0; j < 256; ++j) acc += b2[j] * (Wfc[j * 256 + c] + Wfc[(256 + j) * 256 + c]);
        bias[c] = acc;
    }
}

// ---------------------------------------------------------------------------
// K7: 8 pairs per block; M1/M2 columns shared across the 8 pairs.
// ---------------------------------------------------------------------------
__global__ void k_final(const float* __restrict__ pairfeat,
                        const float* __restrict__ M1, const float* __restrict__ M2,
                        const float* __restrict__ bias,
                        float* __restrict__ out) {
    __shared__ float a1s[8][HID];
    __shared__ float a2s[8][HID];
    int i0 = blockIdx.x * 8;
    int tid = threadIdx.x;
    int p = tid >> 5, w = tid & 31;
    a1s[p][w] = pairfeat[(size_t)(i0 + p) * HID + w];
    a2s[p][w] = pairfeat[(size_t)(BATCH + i0 + p) * HID + w];
    __syncthreads();

    int c = tid;
    float acc[8];
#pragma unroll
    for (int q = 0; q < 8; ++q) acc[q] = bias[c];
#pragma unroll
    for (int k = 0; k < HID; ++k) {
        float m1 = M1[k * 256 + c];
        float m2 = M2[k * 256 + c];
#pragma unroll
        for (int q = 0; q < 8; ++q)
            acc[q] += a1s[q][k] * m1 + a2s[q][k] * m2;
    }
#pragma unroll
    for (int q = 0; q < 8; ++q)
        out[(size_t)(i0 + q) * 256 + c] = fmaxf(acc[q], 0.f);
}

// ---------------------------------------------------------------------------
extern "C" void kernel_launch(void* const* d_in, const int* in_sizes, int n_in,
                              void* d_out, int out_size, void* d_ws, size_t ws_size,
                              hipStream_t stream) {
    const int*   idx   = (const int*)d_in[0];
    const int*   src   = (const int*)d_in[1];
    const int*   dst   = (const int*)d_in[2];
    const int*   g1    = (const int*)d_in[3];
    const int*   g2    = (const int*)d_in[4];
    const float* embed = (const float*)d_in[5];
    const float* W1    = (const float*)d_in[6];
    const float* b1    = (const float*)d_in[7];
    const float* W2    = (const float*)d_in[8];
    const float* b2    = (const float*)d_in[9];
    const float* Wfc   = (const float*)d_in[10];
    const float* bfc   = (const float*)d_in[11];
    float* out = (float*)d_out;

    char* ws = (char*)d_ws;
    u16t*  tmpb     = (u16t*)ws;   ws += (size_t)NUM_EMBED * HID * 2;        // 3.5 MB
    u16t*  feat1    = (u16t*)ws;   ws += (size_t)N_NODES * HID * 2;          // 4.2 MB
    float* agg1     = (float*)ws;  ws += (size_t)N_NODES * HID * 4;          // 8 MB  } one memset
    float* agg2ov   = (float*)ws;  ws += (size_t)N_NODES * HID * 4;          // 8 MB  }
    float* pairfeat = (float*)ws;  ws += (size_t)2 * BATCH * HID * 4;        // 1 MB
    float* M1       = (float*)ws;  ws += 32 * 256 * 4;
    float* M2       = (float*)ws;  ws += 32 * 256 * 4;
    float* bias     = (float*)ws;  ws += 256 * 4;
    int*   cnt      = (int*)ws;    ws += (size_t)NG * N_NODES * 4;           // 2 MB  } one memset
    int*   ovf_cnt  = (int*)ws;    ws += 64;                                 //       }
    u16t*  bins     = (u16t*)ws;   ws += (size_t)NG * N_NODES * CAP * 2;     // 8 MB
    int*   ovf      = (int*)ws;    ws += (size_t)OVF_CAP * 4;                // 256 KB

    hipMemsetAsync(cnt, 0, (size_t)NG * N_NODES * 4 + 64, stream);
    hipMemsetAsync(agg1, 0, (size_t)2 * N_NODES * HID * sizeof(float), stream);

    k_bin<<<N_EDGES / 256, 256, 0, stream>>>(src, dst, cnt, bins, ovf_cnt, ovf);
    k_embed_w1<<<(NUM_EMBED + 127) / 128, 256, 0, stream>>>(embed, W1, tmpb);
    k_fold<<<65, 256, 0, stream>>>(W2, b2, Wfc, bfc, M1, M2, bias);
    k_gather<<<(N_NODES * 16) / 256, 256, 0, stream>>>((const u32t*)tmpb, idx, (u32t*)feat1);

    k_ovf1<<<64, 256, 0, stream>>>(feat1, ovf_cnt, ovf, agg1);
    k_spmm1<<<(N_NODES * 32) / 256, 256, 0, stream>>>(feat1, cnt, bins, b1, agg1);
    k_ovf2<<<64, 256, 0, stream>>>(agg1, ovf_cnt, ovf, agg2ov);
    k_spmm2b<<<(2 * BATCH * 32) / 256, 256, 0, stream>>>(agg1, cnt, bins, g1, g2, agg2ov, pairfeat);

    k_final<<<BATCH / 8, 256, 0, stream>>>(pairfeat, M1, M2, bias, out);
}

// Round 7
// 131.691 us; speedup vs baseline: 3.7167x; 1.1209x over previous
//
#include <hip/hip_runtime.h>

#define IN_FEATS 256
#define HID 32
#define NUM_EMBED 54012
#define N_NODES 65536
#define N_EDGES 1048576
#define BATCH 4096

#define NR 256            // node ranges (dst >> 8), 256 nodes each
#define NB 256            // histogram/scatter blocks
#define EPB (N_EDGES / NB)  // 4096 edges per block
#define CAP2 32           // slots per node (deg ~ Poisson(16); P(>32) ~ 1e-4)
#define OVF_CAP 65536

typedef unsigned short u16t;
typedef unsigned int u32t;

__device__ __forceinline__ float bf2f(u16t u) {
    return __uint_as_float(((u32t)u) << 16);
}
__device__ __forceinline__ u16t f2bf(float f) {
    u32t x = __float_as_uint(f);
    return (u16t)((x + 0x7FFFu + ((x >> 16) & 1u)) >> 16);   // RNE
}

// ---------------------------------------------------------------------------
// K1: tmpb[r][c] = bf16( sum_k embed[r][k] * W1[k][c] )   (54012 x 32)
// ---------------------------------------------------------------------------
__global__ void k_embed_w1(const float* __restrict__ embed,
                           const float* __restrict__ W1,
                           u16t* __restrict__ tmpb) {
    __shared__ float w1s[IN_FEATS * HID];
    int tid = threadIdx.x;
    for (int i = tid; i < IN_FEATS * HID / 4; i += 256)
        ((float4*)w1s)[i] = ((const float4*)W1)[i];
    __syncthreads();

    int rg = tid >> 3;
    int cg = tid & 7;
    int r0 = blockIdx.x * 128 + rg * 4;
    int c0 = cg * 4;

    int ra = min(r0 + 0, NUM_EMBED - 1);
    int rb = min(r0 + 1, NUM_EMBED - 1);
    int rc = min(r0 + 2, NUM_EMBED - 1);
    int rd = min(r0 + 3, NUM_EMBED - 1);
    const float4* E0 = (const float4*)(embed + (size_t)ra * IN_FEATS);
    const float4* E1 = (const float4*)(embed + (size_t)rb * IN_FEATS);
    const float4* E2 = (const float4*)(embed + (size_t)rc * IN_FEATS);
    const float4* E3 = (const float4*)(embed + (size_t)rd * IN_FEATS);

    float4 a0 = {0,0,0,0}, a1 = {0,0,0,0}, a2 = {0,0,0,0}, a3 = {0,0,0,0};

#define FMA4(ACC, S, W) \
    ACC.x += (S) * (W).x; ACC.y += (S) * (W).y; ACC.z += (S) * (W).z; ACC.w += (S) * (W).w;

    for (int k4 = 0; k4 < IN_FEATS / 4; ++k4) {
        float4 e0 = E0[k4], e1 = E1[k4], e2 = E2[k4], e3 = E3[k4];
        const float4* wr = (const float4*)(w1s + (k4 * 4) * HID) + cg;
        float4 w;
        w = wr[0];  FMA4(a0, e0.x, w) FMA4(a1, e1.x, w) FMA4(a2, e2.x, w) FMA4(a3, e3.x, w)
        w = wr[8];  FMA4(a0, e0.y, w) FMA4(a1, e1.y, w) FMA4(a2, e2.y, w) FMA4(a3, e3.y, w)
        w = wr[16]; FMA4(a0, e0.z, w) FMA4(a1, e1.z, w) FMA4(a2, e2.z, w) FMA4(a3, e3.z, w)
        w = wr[24]; FMA4(a0, e0.w, w) FMA4(a1, e1.w, w) FMA4(a2, e2.w, w) FMA4(a3, e3.w, w)
    }
#undef FMA4

#define ST4(R, A) \
    if (R < NUM_EMBED) { \
        ushort4 s4 = make_ushort4(f2bf(A.x), f2bf(A.y), f2bf(A.z), f2bf(A.w)); \
        *(ushort4*)(tmpb + (size_t)(R) * HID + c0) = s4; \
    }
    ST4(r0 + 0, a0)
    ST4(r0 + 1, a1)
    ST4(r0 + 2, a2)
    ST4(r0 + 3, a3)
#undef ST4
}

// ---------------------------------------------------------------------------
// K2: feat1[n][:] = tmpb[idx[n]][:]   (bf16 rows, 64B, 16 u32 lanes per row)
// ---------------------------------------------------------------------------
__global__ void k_gather(const u32t* __restrict__ tmpu,
                         const int* __restrict__ idx,
                         u32t* __restrict__ feat1u) {
    int t = blockIdx.x * 256 + threadIdx.x;
    int n = t >> 4, j = t & 15;
    feat1u[((size_t)n << 4) + j] = tmpu[((size_t)idx[n] << 4) + j];
}

// ---------------------------------------------------------------------------
// Sort pass 1: per-block LDS histogram over dst>>8.  hist[block][range]
// ---------------------------------------------------------------------------
__global__ void k_hist(const int* __restrict__ dst, u32t* __restrict__ hist) {
    __shared__ u32t h[NR];
    int b = blockIdx.x, t = threadIdx.x;
    h[t] = 0;
    __syncthreads();
    int base = b * EPB;
#pragma unroll 4
    for (int k = 0; k < EPB / 256; ++k) {
        int d = __builtin_nontemporal_load(&dst[base + k * 256 + t]);
        atomicAdd(&h[d >> 8], 1u);
    }
    __syncthreads();
    hist[b * NR + t] = h[t];
}

// ---------------------------------------------------------------------------
// Sort pass 2 (1 block): gstart[b][r] = global exclusive offset (r-major,
// b-minor).  Column sums are coalesced row loads; scan in LDS.
// ---------------------------------------------------------------------------
__global__ void k_scan(const u32t* __restrict__ hist, u32t* __restrict__ gstart) {
    __shared__ u32t T[NR];
    int r = threadIdx.x;
    u32t tot = 0;
    for (int b = 0; b < NB; ++b) tot += hist[b * NR + r];
    T[r] = tot;
    __syncthreads();
    for (int off = 1; off < NR; off <<= 1) {
        u32t x = (r >= off) ? T[r - off] : 0;
        __syncthreads();
        T[r] += x;
        __syncthreads();
    }
    u32t run = T[r] - tot;   // exclusive prefix over ranges
    for (int b = 0; b < NB; ++b) {
        u32t h = hist[b * NR + r];
        gstart[b * NR + r] = run;
        run += h;
    }
}

// ---------------------------------------------------------------------------
// Sort pass 3: scatter packed (src | dstlow<<16) into range-contiguous
// sorted[]. Cursors live in LDS (zero global atomics); per-(block,range)
// runs of ~16 edges = 64B -> coalesced-ish.
// ---------------------------------------------------------------------------
__global__ void k_scatter_s(const int* __restrict__ src, const int* __restrict__ dst,
                            const u32t* __restrict__ gstart, u32t* __restrict__ sorted) {
    __shared__ u32t cur[NR];
    int b = blockIdx.x, t = threadIdx.x;
    cur[t] = gstart[b * NR + t];
    __syncthreads();
    int base = b * EPB;
#pragma unroll 4
    for (int k = 0; k < EPB / 256; ++k) {
        int e = base + k * 256 + t;
        int s = __builtin_nontemporal_load(&src[e]);
        int d = __builtin_nontemporal_load(&dst[e]);
        u32t p = atomicAdd(&cur[d >> 8], 1u);
        sorted[p] = (u32t)s | ((u32t)(d & 255) << 16);
    }
}

// ---------------------------------------------------------------------------
// Sort pass 4: one block per range; pack segment into LDS cells
// [256 nodes][32 u16 slots] via LDS atomics, flush coalesced.
// ---------------------------------------------------------------------------
__global__ void k_pack(const u32t* __restrict__ gstart, const u32t* __restrict__ sorted,
                       int* __restrict__ cnt, u16t* __restrict__ bins,
                       int* __restrict__ ovf_cnt, int* __restrict__ ovf) {
    __shared__ u16t cells[NR * CAP2];   // 16 KB
    __shared__ u32t cl[NR];             // 1 KB
    int r = blockIdx.x, t = threadIdx.x;
    for (int i = t; i < NR * CAP2 / 2; i += 256) ((u32t*)cells)[i] = 0;
    cl[t] = 0;
    __syncthreads();

    u32t beg = gstart[r];                                  // gstart[0][r]
    u32t end = (r < NR - 1) ? gstart[r + 1] : N_EDGES;
    for (u32t i = beg + t; i < end; i += 256) {
        u32t w = sorted[i];
        int dl = (int)(w >> 16) & 255;
        u32t p = atomicAdd(&cl[dl], 1u);
        if (p < CAP2) {
            cells[dl * CAP2 + p] = (u16t)(w & 0xFFFFu);
        } else {
            int o = atomicAdd(ovf_cnt, 1);
            u32t dfull = ((u32t)r << 8) | (u32t)dl;
            if (o < OVF_CAP) ovf[o] = (int)((w & 0xFFFFu) | (dfull << 16));
        }
    }
    __syncthreads();
    for (int i = t; i < NR * CAP2 / 2; i += 256)
        ((u32t*)(bins + ((size_t)r << 13)))[i] = ((const u32t*)cells)[i];
    cnt[(r << 8) + t] = min((int)cl[t], CAP2);
}

// ---------------------------------------------------------------------------
// Overflow pre-accumulation (rare, ~tens of edges): f32 atomics.
// ---------------------------------------------------------------------------
__global__ void k_ovf1(const u16t* __restrict__ feat1,
                       const int* __restrict__ ovf_cnt, const int* __restrict__ ovf,
                       float* __restrict__ agg1) {
    int total = min(*ovf_cnt, OVF_CAP);
    int t = blockIdx.x * 256 + threadIdx.x;
    int c = t & 31;
    for (int i = t >> 5; i < total; i += 512) {
        unsigned p = (unsigned)ovf[i];
        int s = p & 0xFFFFu;
        int d = p >> 16;
        atomicAdd(&agg1[((size_t)d << 5) + c], bf2f(feat1[((size_t)s << 5) + c]));
    }
}

__global__ void k_ovf2(const float* __restrict__ agg1,
                       const int* __restrict__ ovf_cnt, const int* __restrict__ ovf,
                       float* __restrict__ agg2ov) {
    int total = min(*ovf_cnt, OVF_CAP);
    int t = blockIdx.x * 256 + threadIdx.x;
    int c = t & 31;
    for (int i = t >> 5; i < total; i += 512) {
        unsigned p = (unsigned)ovf[i];
        int s = p & 0xFFFFu;
        int d = p >> 16;
        atomicAdd(&agg2ov[((size_t)d << 5) + c], agg1[((size_t)s << 5) + c]);
    }
}

// ---------------------------------------------------------------------------
// SpMM1: agg1[v][c] = relu(agg1[v][c](=ovf) + sum_slots feat1[s][c] + b1[c])
// One cnt load + one 64B cell line per node; 16 unconditional independent
// row loads (cells zero-filled -> row 0, masked x0), tail branch for m>16.
// ---------------------------------------------------------------------------
__global__ void k_spmm1(const u16t* __restrict__ feat1,
                        const int* __restrict__ cnt, const u16t* __restrict__ bins,
                        const float* __restrict__ b1, float* __restrict__ agg1) {
    int t = blockIdx.x * 256 + threadIdx.x;
    int v = t >> 5, c = t & 31;
    int m = cnt[v];
    const int4* cell = (const int4*)(bins + ((size_t)v << 5));
    u32t w[8];
    *(int4*)(w + 0) = cell[0];
    *(int4*)(w + 4) = cell[1];
    float va[16];
#pragma unroll
    for (int k = 0; k < 8; ++k) {
        va[2 * k + 0] = bf2f(feat1[((size_t)(w[k] & 0xFFFFu) << 5) + c]);
        va[2 * k + 1] = bf2f(feat1[((size_t)(w[k] >> 16) << 5) + c]);
    }
    float acc = 0.f;
#pragma unroll
    for (int j = 0; j < 16; ++j) acc += (m > j) ? va[j] : 0.f;
    if (m > 16) {
        u32t w2[8];
        *(int4*)(w2 + 0) = cell[2];
        *(int4*)(w2 + 4) = cell[3];
        float vb[16];
#pragma unroll
        for (int k = 0; k < 8; ++k) {
            vb[2 * k + 0] = bf2f(feat1[((size_t)(w2[k] & 0xFFFFu) << 5) + c]);
            vb[2 * k + 1] = bf2f(feat1[((size_t)(w2[k] >> 16) << 5) + c]);
        }
#pragma unroll
        for (int j = 0; j < 16; ++j) acc += (m > 16 + j) ? vb[j] : 0.f;
    }
    agg1[t] = fmaxf(agg1[t] + acc + b1[c], 0.f);
}

// ---------------------------------------------------------------------------
// SpMM2 over the 8192 batch slots only (agg1 rows f32, 128B).
// ---------------------------------------------------------------------------
__global__ void k_spmm2b(const float* __restrict__ agg1,
                         const int* __restrict__ cnt, const u16t* __restrict__ bins,
                         const int* __restrict__ g1, const int* __restrict__ g2,
                         const float* __restrict__ agg2ov,
                         float* __restrict__ pairfeat) {
    int t = blockIdx.x * 256 + threadIdx.x;
    int slot = t >> 5, c = t & 31;
    int v = (slot < BATCH) ? g1[slot] : g2[slot - BATCH];
    int m = cnt[v];
    const int4* cell = (const int4*)(bins + ((size_t)v << 5));
    u32t w[8];
    *(int4*)(w + 0) = cell[0];
    *(int4*)(w + 4) = cell[1];
    float va[16];
#pragma unroll
    for (int k = 0; k < 8; ++k) {
        va[2 * k + 0] = agg1[((size_t)(w[k] & 0xFFFFu) << 5) + c];
        va[2 * k + 1] = agg1[((size_t)(w[k] >> 16) << 5) + c];
    }
    float acc = agg2ov[((size_t)v << 5) + c];
#pragma unroll
    for (int j = 0; j < 16; ++j) acc += (m > j) ? va[j] : 0.f;
    if (m > 16) {
        u32t w2[8];
        *(int4*)(w2 + 0) = cell[2];
        *(int4*)(w2 + 4) = cell[3];
        float vb[16];
#pragma unroll
        for (int k = 0; k < 8; ++k) {
            vb[2 * k + 0] = agg1[((size_t)(w2[k] & 0xFFFFu) << 5) + c];
            vb[2 * k + 1] = agg1[((size_t)(w2[k] >> 16) << 5) + c];
        }
#pragma unroll
        for (int j = 0; j < 16; ++j) acc += (m > 16 + j) ? vb[j] : 0.f;
    }
    pairfeat[t] = acc;
}

// ---------------------------------------------------------------------------
// K6: fold W2/Wfc/b2/bfc into M1[32,256], M2[32,256], bias[256]
// ---------------------------------------------------------------------------
__global__ void k_fold(const float* __restrict__ W2, const float* __restrict__ b2,
                       const float* __restrict__ Wfc, const float* __restrict__ bfc,
                       float* __restrict__ M1, float* __restrict__ M2,
                       float* __restrict__ bias) {
    int c = threadIdx.x;
    int r = blockIdx.x;
    if (r < 32) {
        float acc = 0.f;
        for (int j = 0; j < 256; ++j) acc += W2[r * 256 + j] * Wfc[j * 256 + c];
        M1[r * 256 + c] = acc;
    } else if (r < 64) {
        int k = r - 32;
        float acc = 0.f;
        for (int j = 0; j < 256; ++j) acc += W2[k * 256 + j] * Wfc[(256 + j) * 256 + c];
        M2[k * 256 + c] = acc;
    } else {
        float acc = bfc[c];
        for (int j = 0; j < 256; ++j) acc += b2[j] * (Wfc[j * 256 + c] + Wfc[(256 + j) * 256 + c]);
        bias[c] = acc;
    }
}

// ---------------------------------------------------------------------------
// K7: 8 pairs per block; M1/M2 columns shared across the 8 pairs.
// ---------------------------------------------------------------------------
__global__ void k_final(const float* __restrict__ pairfeat,
                        const float* __restrict__ M1, const float* __restrict__ M2,
                        const float* __restrict__ bias,
                        float* __restrict__ out) {
    __shared__ float a1s[8][HID];
    __shared__ float a2s[8][HID];
    int i0 = blockIdx.x * 8;
    int tid = threadIdx.x;
    int p = tid >> 5, w = tid & 31;
    a1s[p][w] = pairfeat[(size_t)(i0 + p) * HID + w];
    a2s[p][w] = pairfeat[(size_t)(BATCH + i0 + p) * HID + w];
    __syncthreads();

    int c = tid;
    float acc[8];
#pragma unroll
    for (int q = 0; q < 8; ++q) acc[q] = bias[c];
#pragma unroll
    for (int k = 0; k < HID; ++k) {
        float m1 = M1[k * 256 + c];
        float m2 = M2[k * 256 + c];
#pragma unroll
        for (int q = 0; q < 8; ++q)
            acc[q] += a1s[q][k] * m1 + a2s[q][k] * m2;
    }
#pragma unroll
    for (int q = 0; q < 8; ++q)
        out[(size_t)(i0 + q) * 256 + c] = fmaxf(acc[q], 0.f);
}

// ---------------------------------------------------------------------------
extern "C" void kernel_launch(void* const* d_in, const int* in_sizes, int n_in,
                              void* d_out, int out_size, void* d_ws, size_t ws_size,
                              hipStream_t stream) {
    const int*   idx   = (const int*)d_in[0];
    const int*   src   = (const int*)d_in[1];
    const int*   dst   = (const int*)d_in[2];
    const int*   g1    = (const int*)d_in[3];
    const int*   g2    = (const int*)d_in[4];
    const float* embed = (const float*)d_in[5];
    const float* W1    = (const float*)d_in[6];
    const float* b1    = (const float*)d_in[7];
    const float* W2    = (const float*)d_in[8];
    const float* b2    = (const float*)d_in[9];
    const float* Wfc   = (const float*)d_in[10];
    const float* bfc   = (const float*)d_in[11];
    float* out = (float*)d_out;

    char* ws = (char*)d_ws;
    u16t*  tmpb     = (u16t*)ws;   ws += (size_t)NUM_EMBED * HID * 2;        // 3.5 MB
    u16t*  feat1    = (u16t*)ws;   ws += (size_t)N_NODES * HID * 2;          // 4 MB
    float* agg1     = (float*)ws;  ws += (size_t)N_NODES * HID * 4;          // 8 MB  } one memset
    float* agg2ov   = (float*)ws;  ws += (size_t)N_NODES * HID * 4;          // 8 MB  }
    float* pairfeat = (float*)ws;  ws += (size_t)2 * BATCH * HID * 4;        // 1 MB
    float* M1       = (float*)ws;  ws += 32 * 256 * 4;
    float* M2       = (float*)ws;  ws += 32 * 256 * 4;
    float* bias     = (float*)ws;  ws += 256 * 4;
    u32t*  hist     = (u32t*)ws;   ws += (size_t)NB * NR * 4;                // 256 KB
    u32t*  gstart   = (u32t*)ws;   ws += (size_t)NB * NR * 4;                // 256 KB
    u32t*  sorted   = (u32t*)ws;   ws += (size_t)N_EDGES * 4;                // 4 MB
    int*   cnt      = (int*)ws;    ws += (size_t)N_NODES * 4;                // 256 KB
    u16t*  bins     = (u16t*)ws;   ws += (size_t)N_NODES * CAP2 * 2;         // 4 MB
    int*   ovf_cnt  = (int*)ws;    ws += 64;
    int*   ovf      = (int*)ws;    ws += (size_t)OVF_CAP * 4;                // 256 KB

    hipMemsetAsync(ovf_cnt, 0, 64, stream);
    hipMemsetAsync(agg1, 0, (size_t)2 * N_NODES * HID * sizeof(float), stream);

    // atomic-free binning: hist -> scan -> range-scatter -> pack
    k_hist<<<NB, 256, 0, stream>>>(dst, hist);
    k_scan<<<1, NR, 0, stream>>>(hist, gstart);
    k_scatter_s<<<NB, 256, 0, stream>>>(src, dst, gstart, sorted);
    k_pack<<<NR, 256, 0, stream>>>(gstart, sorted, cnt, bins, ovf_cnt, ovf);

    // dense prep
    k_embed_w1<<<(NUM_EMBED + 127) / 128, 256, 0, stream>>>(embed, W1, tmpb);
    k_fold<<<65, 256, 0, stream>>>(W2, b2, Wfc, bfc, M1, M2, bias);
    k_gather<<<(N_NODES * 16) / 256, 256, 0, stream>>>((const u32t*)tmpb, idx, (u32t*)feat1);

    // SpMMs
    k_ovf1<<<64, 256, 0, stream>>>(feat1, ovf_cnt, ovf, agg1);
    k_spmm1<<<(N_NODES * 32) / 256, 256, 0, stream>>>(feat1, cnt, bins, b1, agg1);
    k_ovf2<<<64, 256, 0, stream>>>(agg1, ovf_cnt, ovf, agg2ov);
    k_spmm2b<<<(2 * BATCH * 32) / 256, 256, 0, stream>>>(agg1, cnt, bins, g1, g2, agg2ov, pairfeat);

    k_final<<<BATCH / 8, 256, 0, stream>>>(pairfeat, M1, M2, bias, out);
}

// Round 8
// 116.304 us; speedup vs baseline: 4.2084x; 1.1323x over previous
//
#include <hip/hip_runtime.h>

#define IN_FEATS 256
#define HID 32
#define NUM_EMBED 54012
#define N_NODES 65536
#define N_EDGES 1048576
#define BATCH 4096

#define NR 256              // node ranges (dst >> 8), 256 nodes each
#define NB 256              // histogram/scatter blocks
#define EPB (N_EDGES / NB)  // 4096 edges per block
#define CAP2 32             // slots per node (deg ~ Poisson(16); P(>32) ~ 1e-4)
#define OVF_CAP 65536

typedef unsigned short u16t;
typedef unsigned int u32t;

__device__ __forceinline__ float bf2f(u16t u) {
    return __uint_as_float(((u32t)u) << 16);
}
__device__ __forceinline__ u16t f2bf(float f) {
    u32t x = __float_as_uint(f);
    return (u16t)((x + 0x7FFFu + ((x >> 16) & 1u)) >> 16);   // RNE
}

// ---------------------------------------------------------------------------
// K0: zero agg1+agg2ov (contiguous, 16.8 MB) + ovf_cnt. Grid-stride float4.
// ---------------------------------------------------------------------------
__global__ void k_zero(float4* __restrict__ p, int n4, int* __restrict__ ovf_cnt) {
    int t = blockIdx.x * 256 + threadIdx.x;
    if (t == 0) *ovf_cnt = 0;
    float4 z = {0.f, 0.f, 0.f, 0.f};
    for (int i = t; i < n4; i += 1024 * 256) p[i] = z;
}

// ---------------------------------------------------------------------------
// K1: tmpb[r][c] = bf16( sum_k embed[r][k] * W1[k][c] )   (54012 x 32)
// 256 threads = 32 row-groups x 8 col-groups; 2 rows x 4 cols per thread.
// 64 rows/block -> 844 blocks (~3.3 blocks/CU, vs 422 @ 12% occupancy).
// ---------------------------------------------------------------------------
__global__ void k_embed_w1(const float* __restrict__ embed,
                           const float* __restrict__ W1,
                           u16t* __restrict__ tmpb) {
    __shared__ float w1s[IN_FEATS * HID];
    int tid = threadIdx.x;
    for (int i = tid; i < IN_FEATS * HID / 4; i += 256)
        ((float4*)w1s)[i] = ((const float4*)W1)[i];
    __syncthreads();

    int rg = tid >> 3;                    // 0..31
    int cg = tid & 7;                     // 0..7
    int r0 = blockIdx.x * 64 + rg * 2;
    int c0 = cg * 4;

    int ra = min(r0 + 0, NUM_EMBED - 1);
    int rb = min(r0 + 1, NUM_EMBED - 1);
    const float4* E0 = (const float4*)(embed + (size_t)ra * IN_FEATS);
    const float4* E1 = (const float4*)(embed + (size_t)rb * IN_FEATS);

    float4 a0 = {0,0,0,0}, a1 = {0,0,0,0};

#define FMA4(ACC, S, W) \
    ACC.x += (S) * (W).x; ACC.y += (S) * (W).y; ACC.z += (S) * (W).z; ACC.w += (S) * (W).w;

    for (int k4 = 0; k4 < IN_FEATS / 4; ++k4) {
        float4 e0 = E0[k4], e1 = E1[k4];
        const float4* wr = (const float4*)(w1s + (k4 * 4) * HID) + cg;
        float4 w;
        w = wr[0];  FMA4(a0, e0.x, w) FMA4(a1, e1.x, w)
        w = wr[8];  FMA4(a0, e0.y, w) FMA4(a1, e1.y, w)
        w = wr[16]; FMA4(a0, e0.z, w) FMA4(a1, e1.z, w)
        w = wr[24]; FMA4(a0, e0.w, w) FMA4(a1, e1.w, w)
    }
#undef FMA4

#define ST4(R, A) \
    if (R < NUM_EMBED) { \
        ushort4 s4 = make_ushort4(f2bf(A.x), f2bf(A.y), f2bf(A.z), f2bf(A.w)); \
        *(ushort4*)(tmpb + (size_t)(R) * HID + c0) = s4; \
    }
    ST4(r0 + 0, a0)
    ST4(r0 + 1, a1)
#undef ST4
}

// ---------------------------------------------------------------------------
// K2: feat1[n][:] = tmpb[idx[n]][:]   (bf16 rows, 64B, 16 u32 lanes per row)
// ---------------------------------------------------------------------------
__global__ void k_gather(const u32t* __restrict__ tmpu,
                         const int* __restrict__ idx,
                         u32t* __restrict__ feat1u) {
    int t = blockIdx.x * 256 + threadIdx.x;
    int n = t >> 4, j = t & 15;
    feat1u[((size_t)n << 4) + j] = tmpu[((size_t)idx[n] << 4) + j];
}

// ---------------------------------------------------------------------------
// Sort pass 1: per-block LDS histogram over dst>>8.  hist[block][range]
// ---------------------------------------------------------------------------
__global__ void k_hist(const int* __restrict__ dst, u32t* __restrict__ hist) {
    __shared__ u32t h[NR];
    int b = blockIdx.x, t = threadIdx.x;
    h[t] = 0;
    __syncthreads();
    int base = b * EPB;
#pragma unroll 4
    for (int k = 0; k < EPB / 256; ++k) {
        int d = __builtin_nontemporal_load(&dst[base + k * 256 + t]);
        atomicAdd(&h[d >> 8], 1u);
    }
    __syncthreads();
    hist[b * NR + t] = h[t];
}

// ---------------------------------------------------------------------------
// Sort pass 2a: one block per range r: scan hist[:,r] over blocks.
// pstart[b][r] = exclusive prefix; tot[r] = column total.
// ---------------------------------------------------------------------------
__global__ void k_scan_a(const u32t* __restrict__ hist, u32t* __restrict__ pstart,
                         u32t* __restrict__ tot) {
    __shared__ u32t T[NB];
    int r = blockIdx.x, t = threadIdx.x;        // t = block index b
    u32t v = hist[t * NR + r];
    T[t] = v;
    __syncthreads();
    for (int off = 1; off < NB; off <<= 1) {
        u32t x = (t >= off) ? T[t - off] : 0;
        __syncthreads();
        T[t] += x;
        __syncthreads();
    }
    pstart[t * NR + r] = T[t] - v;
    if (t == NB - 1) tot[r] = T[t];
}

// ---------------------------------------------------------------------------
// Sort pass 2b (1 block): roff[r] = exclusive prefix of tot; roff[NR]=N_EDGES.
// ---------------------------------------------------------------------------
__global__ void k_scan_b(const u32t* __restrict__ tot, u32t* __restrict__ roff) {
    __shared__ u32t T[NR];
    int r = threadIdx.x;
    u32t v = tot[r];
    T[r] = v;
    __syncthreads();
    for (int off = 1; off < NR; off <<= 1) {
        u32t x = (r >= off) ? T[r - off] : 0;
        __syncthreads();
        T[r] += x;
        __syncthreads();
    }
    roff[r + 1] = T[r];
    if (r == 0) roff[0] = 0;
}

// ---------------------------------------------------------------------------
// Sort pass 3: scatter packed (src | dstlow<<16) into range-contiguous
// sorted[]. Cursors in LDS; zero global atomics.
// ---------------------------------------------------------------------------
__global__ void k_scatter_s(const int* __restrict__ src, const int* __restrict__ dst,
                            const u32t* __restrict__ pstart, const u32t* __restrict__ roff,
                            u32t* __restrict__ sorted) {
    __shared__ u32t cur[NR];
    int b = blockIdx.x, t = threadIdx.x;
    cur[t] = roff[t] + pstart[b * NR + t];
    __syncthreads();
    int base = b * EPB;
#pragma unroll 4
    for (int k = 0; k < EPB / 256; ++k) {
        int e = base + k * 256 + t;
        int s = __builtin_nontemporal_load(&src[e]);
        int d = __builtin_nontemporal_load(&dst[e]);
        u32t p = atomicAdd(&cur[d >> 8], 1u);
        sorted[p] = (u32t)s | ((u32t)(d & 255) << 16);
    }
}

// ---------------------------------------------------------------------------
// Sort pass 4: one block per range; pack segment into LDS cells
// [256 nodes][32 u16 slots] via LDS atomics, flush coalesced.
// ---------------------------------------------------------------------------
__global__ void k_pack(const u32t* __restrict__ roff, const u32t* __restrict__ sorted,
                       int* __restrict__ cnt, u16t* __restrict__ bins,
                       int* __restrict__ ovf_cnt, int* __restrict__ ovf) {
    __shared__ u16t cells[NR * CAP2];   // 16 KB
    __shared__ u32t cl[NR];             // 1 KB
    int r = blockIdx.x, t = threadIdx.x;
    for (int i = t; i < NR * CAP2 / 2; i += 256) ((u32t*)cells)[i] = 0;
    cl[t] = 0;
    __syncthreads();

    u32t beg = roff[r];
    u32t end = roff[r + 1];
    for (u32t i = beg + t; i < end; i += 256) {
        u32t w = sorted[i];
        int dl = (int)(w >> 16) & 255;
        u32t p = atomicAdd(&cl[dl], 1u);
        if (p < CAP2) {
            cells[dl * CAP2 + p] = (u16t)(w & 0xFFFFu);
        } else {
            int o = atomicAdd(ovf_cnt, 1);
            u32t dfull = ((u32t)r << 8) | (u32t)dl;
            if (o < OVF_CAP) ovf[o] = (int)((w & 0xFFFFu) | (dfull << 16));
        }
    }
    __syncthreads();
    for (int i = t; i < NR * CAP2 / 2; i += 256)
        ((u32t*)(bins + ((size_t)r << 13)))[i] = ((const u32t*)cells)[i];
    cnt[(r << 8) + t] = min((int)cl[t], CAP2);
}

// ---------------------------------------------------------------------------
// Overflow pre-accumulation (rare, ~tens of edges): f32 atomics.
// ---------------------------------------------------------------------------
__global__ void k_ovf1(const u16t* __restrict__ feat1,
                       const int* __restrict__ ovf_cnt, const int* __restrict__ ovf,
                       float* __restrict__ agg1) {
    int total = min(*ovf_cnt, OVF_CAP);
    int t = blockIdx.x * 256 + threadIdx.x;
    int c = t & 31;
    for (int i = t >> 5; i < total; i += 512) {
        unsigned p = (unsigned)ovf[i];
        int s = p & 0xFFFFu;
        int d = p >> 16;
        atomicAdd(&agg1[((size_t)d << 5) + c], bf2f(feat1[((size_t)s << 5) + c]));
    }
}

__global__ void k_ovf2(const float* __restrict__ agg1,
                       const int* __restrict__ ovf_cnt, const int* __restrict__ ovf,
                       float* __restrict__ agg2ov) {
    int total = min(*ovf_cnt, OVF_CAP);
    int t = blockIdx.x * 256 + threadIdx.x;
    int c = t & 31;
    for (int i = t >> 5; i < total; i += 512) {
        unsigned p = (unsigned)ovf[i];
        int s = p & 0xFFFFu;
        int d = p >> 16;
        atomicAdd(&agg2ov[((size_t)d << 5) + c], agg1[((size_t)s << 5) + c]);
    }
}

// ---------------------------------------------------------------------------
// SpMM1: agg1[v][c] = relu(agg1[v][c](=ovf) + sum_slots feat1[s][c] + b1[c])
// ---------------------------------------------------------------------------
__global__ void k_spmm1(const u16t* __restrict__ feat1,
                        const int* __restrict__ cnt, const u16t* __restrict__ bins,
                        const float* __restrict__ b1, float* __restrict__ agg1) {
    int t = blockIdx.x * 256 + threadIdx.x;
    int v = t >> 5, c = t & 31;
    int m = cnt[v];
    const int4* cell = (const int4*)(bins + ((size_t)v << 5));
    u32t w[8];
    *(int4*)(w + 0) = cell[0];
    *(int4*)(w + 4) = cell[1];
    float va[16];
#pragma unroll
    for (int k = 0; k < 8; ++k) {
        va[2 * k + 0] = bf2f(feat1[((size_t)(w[k] & 0xFFFFu) << 5) + c]);
        va[2 * k + 1] = bf2f(feat1[((size_t)(w[k] >> 16) << 5) + c]);
    }
    float acc = 0.f;
#pragma unroll
    for (int j = 0; j < 16; ++j) acc += (m > j) ? va[j] : 0.f;
    if (m > 16) {
        u32t w2[8];
        *(int4*)(w2 + 0) = cell[2];
        *(int4*)(w2 + 4) = cell[3];
        float vb[16];
#pragma unroll
        for (int k = 0; k < 8; ++k) {
            vb[2 * k + 0] = bf2f(feat1[((size_t)(w2[k] & 0xFFFFu) << 5) + c]);
            vb[2 * k + 1] = bf2f(feat1[((size_t)(w2[k] >> 16) << 5) + c]);
        }
#pragma unroll
        for (int j = 0; j < 16; ++j) acc += (m > 16 + j) ? vb[j] : 0.f;
    }
    agg1[t] = fmaxf(agg1[t] + acc + b1[c], 0.f);
}

// ---------------------------------------------------------------------------
// SpMM2 over the 8192 batch slots only (agg1 rows f32, 128B).
// ---------------------------------------------------------------------------
__global__ void k_spmm2b(const float* __restrict__ agg1,
                         const int* __restrict__ cnt, const u16t* __restrict__ bins,
                         const int* __restrict__ g1, const int* __restrict__ g2,
                         const float* __restrict__ agg2ov,
                         float* __restrict__ pairfeat) {
    int t = blockIdx.x * 256 + threadIdx.x;
    int slot = t >> 5, c = t & 31;
    int v = (slot < BATCH) ? g1[slot] : g2[slot - BATCH];
    int m = cnt[v];
    const int4* cell = (const int4*)(bins + ((size_t)v << 5));
    u32t w[8];
    *(int4*)(w + 0) = cell[0];
    *(int4*)(w + 4) = cell[1];
    float va[16];
#pragma unroll
    for (int k = 0; k < 8; ++k) {
        va[2 * k + 0] = agg1[((size_t)(w[k] & 0xFFFFu) << 5) + c];
        va[2 * k + 1] = agg1[((size_t)(w[k] >> 16) << 5) + c];
    }
    float acc = agg2ov[((size_t)v << 5) + c];
#pragma unroll
    for (int j = 0; j < 16; ++j) acc += (m > j) ? va[j] : 0.f;
    if (m > 16) {
        u32t w2[8];
        *(int4*)(w2 + 0) = cell[2];
        *(int4*)(w2 + 4) = cell[3];
        float vb[16];
#pragma unroll
        for (int k = 0; k < 8; ++k) {
            vb[2 * k + 0] = agg1[((size_t)(w2[k] & 0xFFFFu) << 5) + c];
            vb[2 * k + 1] = agg1[((size_t)(w2[k] >> 16) << 5) + c];
        }
#pragma unroll
        for (int j = 0; j < 16; ++j) acc += (m > 16 + j) ? vb[j] : 0.f;
    }
    pairfeat[t] = acc;
}

// ---------------------------------------------------------------------------
// K6: fold W2/Wfc/b2/bfc into M1[32,256], M2[32,256], bias[256]
// ---------------------------------------------------------------------------
__global__ void k_fold(const float* __restrict__ W2, const float* __restrict__ b2,
                       const float* __restrict__ Wfc, const float* __restrict__ bfc,
                       float* __restrict__ M1, float* __restrict__ M2,
                       float* __restrict__ bias) {
    int c = threadIdx.x;
    int r = blockIdx.x;
    if (r < 32) {
        float acc = 0.f;
        for (int j = 0; j < 256; ++j) acc += W2[r * 256 + j] * Wfc[j * 256 + c];
        M1[r * 256 + c] = acc;
    } else if (r < 64) {
        int k = r - 32;
        float acc = 0.f;
        for (int j = 0; j < 256; ++j) acc += W2[k * 256 + j] * Wfc[(256 + j) * 256 + c];
        M2[k * 256 + c] = acc;
    } else {
        float acc = bfc[c];
        for (int j = 0; j < 256; ++j) acc += b2[j] * (Wfc[j * 256 + c] + Wfc[(256 + j) * 256 + c]);
        bias[c] = acc;
    }
}

// ---------------------------------------------------------------------------
// K7: 8 pairs per block; M1/M2 columns shared across the 8 pairs.
// ---------------------------------------------------------------------------
__global__ void k_final(const float* __restrict__ pairfeat,
                        const float* __restrict__ M1, const float* __restrict__ M2,
                        const float* __restrict__ bias,
                        float* __restrict__ out) {
    __shared__ float a1s[8][HID];
    __shared__ float a2s[8][HID];
    int i0 = blockIdx.x * 8;
    int tid = threadIdx.x;
    int p = tid >> 5, w = tid & 31;
    a1s[p][w] = pairfeat[(size_t)(i0 + p) * HID + w];
    a2s[p][w] = pairfeat[(size_t)(BATCH + i0 + p) * HID + w];
    __syncthreads();

    int c = tid;
    float acc[8];
#pragma unroll
    for (int q = 0; q < 8; ++q) acc[q] = bias[c];
#pragma unroll
    for (int k = 0; k < HID; ++k) {
        float m1 = M1[k * 256 + c];
        float m2 = M2[k * 256 + c];
#pragma unroll
        for (int q = 0; q < 8; ++q)
            acc[q] += a1s[q][k] * m1 + a2s[q][k] * m2;
    }
#pragma unroll
    for (int q = 0; q < 8; ++q)
        out[(size_t)(i0 + q) * 256 + c] = fmaxf(acc[q], 0.f);
}

// ---------------------------------------------------------------------------
extern "C" void kernel_launch(void* const* d_in, const int* in_sizes, int n_in,
                              void* d_out, int out_size, void* d_ws, size_t ws_size,
                              hipStream_t stream) {
    const int*   idx   = (const int*)d_in[0];
    const int*   src   = (const int*)d_in[1];
    const int*   dst   = (const int*)d_in[2];
    const int*   g1    = (const int*)d_in[3];
    const int*   g2    = (const int*)d_in[4];
    const float* embed = (const float*)d_in[5];
    const float* W1    = (const float*)d_in[6];
    const float* b1    = (const float*)d_in[7];
    const float* W2    = (const float*)d_in[8];
    const float* b2    = (const float*)d_in[9];
    const float* Wfc   = (const float*)d_in[10];
    const float* bfc   = (const float*)d_in[11];
    float* out = (float*)d_out;

    char* ws = (char*)d_ws;
    u16t*  tmpb     = (u16t*)ws;   ws += (size_t)NUM_EMBED * HID * 2;        // 3.5 MB
    u16t*  feat1    = (u16t*)ws;   ws += (size_t)N_NODES * HID * 2;          // 4 MB
    float* agg1     = (float*)ws;  ws += (size_t)N_NODES * HID * 4;          // 8 MB  } one k_zero
    float* agg2ov   = (float*)ws;  ws += (size_t)N_NODES * HID * 4;          // 8 MB  }
    float* pairfeat = (float*)ws;  ws += (size_t)2 * BATCH * HID * 4;        // 1 MB
    float* M1       = (float*)ws;  ws += 32 * 256 * 4;
    float* M2       = (float*)ws;  ws += 32 * 256 * 4;
    float* bias     = (float*)ws;  ws += 256 * 4;
    u32t*  hist     = (u32t*)ws;   ws += (size_t)NB * NR * 4;                // 256 KB
    u32t*  pstart   = (u32t*)ws;   ws += (size_t)NB * NR * 4;                // 256 KB
    u32t*  tot      = (u32t*)ws;   ws += (size_t)NR * 4;
    u32t*  roff     = (u32t*)ws;   ws += (size_t)(NR + 1) * 4 + 60;
    u32t*  sorted   = (u32t*)ws;   ws += (size_t)N_EDGES * 4;                // 4 MB
    int*   cnt      = (int*)ws;    ws += (size_t)N_NODES * 4;                // 256 KB
    u16t*  bins     = (u16t*)ws;   ws += (size_t)N_NODES * CAP2 * 2;         // 4 MB
    int*   ovf_cnt  = (int*)ws;    ws += 64;
    int*   ovf      = (int*)ws;    ws += (size_t)OVF_CAP * 4;                // 256 KB

    // zero aggs + ovf_cnt (replaces 40us fillBufferAligned)
    k_zero<<<1024, 256, 0, stream>>>((float4*)agg1, 2 * N_NODES * HID / 4, ovf_cnt);

    // atomic-free binning: hist -> scan(a,b) -> range-scatter -> pack
    k_hist<<<NB, 256, 0, stream>>>(dst, hist);
    k_scan_a<<<NR, NB, 0, stream>>>(hist, pstart, tot);
    k_scan_b<<<1, NR, 0, stream>>>(tot, roff);
    k_scatter_s<<<NB, 256, 0, stream>>>(src, dst, pstart, roff, sorted);
    k_pack<<<NR, 256, 0, stream>>>(roff, sorted, cnt, bins, ovf_cnt, ovf);

    // dense prep
    k_embed_w1<<<(NUM_EMBED + 63) / 64, 256, 0, stream>>>(embed, W1, tmpb);
    k_fold<<<65, 256, 0, stream>>>(W2, b2, Wfc, bfc, M1, M2, bias);
    k_gather<<<(N_NODES * 16) / 256, 256, 0, stream>>>((const u32t*)tmpb, idx, (u32t*)feat1);

    // SpMMs
    k_ovf1<<<64, 256, 0, stream>>>(feat1, ovf_cnt, ovf, agg1);
    k_spmm1<<<(N_NODES * 32) / 256, 256, 0, stream>>>(feat1, cnt, bins, b1, agg1);
    k_ovf2<<<64, 256, 0, stream>>>(agg1, ovf_cnt, ovf, agg2ov);
    k_spmm2b<<<(2 * BATCH * 32) / 256, 256, 0, stream>>>(agg1, cnt, bins, g1, g2, agg2ov, pairfeat);

    k_final<<<BATCH / 8, 256, 0, stream>>>(pairfeat, M1, M2, bias, out);
}

// Round 9
// 81.942 us; speedup vs baseline: 5.9731x; 1.4193x over previous
//
#include <hip/hip_runtime.h>

#define IN_FEATS 256
#define HID 32
#define NUM_EMBED 54012
#define N_NODES 65536
#define N_EDGES 1048576
#define BATCH 4096

#define NR 256               // node ranges (dst >> 8), 256 nodes each
#define NB 256               // binsort blocks
#define EPB (N_EDGES / NB)   // 4096 edges per block
#define SEGCAP 4608          // per-range segment capacity (mean 4096, sd 64; +8 sigma)
#define CAP2 32              // bin slots per node (deg ~ Poisson(16))
#define OVF_CAP 65536
#define EMBB 1688            // ceil(54012 / 32) blocks for embed@W1

typedef unsigned short u16t;
typedef unsigned int u32t;

__device__ __forceinline__ float bf2f(u16t u) {
    return __uint_as_float(((u32t)u) << 16);
}
__device__ __forceinline__ u16t f2bf(float f) {
    u32t x = __float_as_uint(f);
    return (u16t)((x + 0x7FFFu + ((x >> 16) & 1u)) >> 16);   // RNE
}

// ---------------------------------------------------------------------------
// K_init: gcur[r] = r*SEGCAP (segment cursors), ovf_cnt = 0.  1 block.
// ---------------------------------------------------------------------------
__global__ void k_init(u32t* __restrict__ gcur, int* __restrict__ ovf_cnt) {
    int t = threadIdx.x;
    gcur[t] = (u32t)t * SEGCAP;
    if (t == 0) *ovf_cnt = 0;
}

// ---------------------------------------------------------------------------
// Phase A (fused, blockIdx-dispatched):
//   [0, NB)            : binsort — LDS hist -> 1 global-atomic reservation per
//                        (block,range) -> LDS-cursor scatter into segments
//   [NB, NB+EMBB)      : tmpb[r][c] = bf16(embed[r] @ W1[:,c]), W1 bf16 in LDS
//   [NB+EMBB, +65)     : fold W2/Wfc/b2/bfc -> M1, M2, bias
// ---------------------------------------------------------------------------
__global__ void k_phaseA(const int* __restrict__ src, const int* __restrict__ dst,
                         u32t* __restrict__ gcur, u32t* __restrict__ sorted,
                         int* __restrict__ ovf_cnt, int* __restrict__ ovf,
                         const float* __restrict__ embed, const float* __restrict__ W1,
                         u16t* __restrict__ tmpb,
                         const float* __restrict__ W2, const float* __restrict__ b2,
                         const float* __restrict__ Wfc, const float* __restrict__ bfc,
                         float* __restrict__ M1, float* __restrict__ M2,
                         float* __restrict__ bias) {
    __shared__ u32t uni[4096];   // 16 KB, role-dependent
    int b = blockIdx.x;
    int t = threadIdx.x;

    if (b < NB) {
        // ---------------- binsort ----------------
        u32t* h   = uni;         // [256]
        u32t* cur = uni + 256;   // [256]
        h[t] = 0;
        __syncthreads();
        int base = b * EPB;
        for (int k = 0; k < EPB / 256; ++k) {
            int d = dst[base + k * 256 + t];
            atomicAdd(&h[d >> 8], 1u);
        }
        __syncthreads();
        cur[t] = atomicAdd(&gcur[t], h[t]);   // reserve contiguous run per range
        __syncthreads();
        for (int k = 0; k < EPB / 256; ++k) {
            int e = base + k * 256 + t;
            int s = src[e];
            int d = dst[e];
            int r = d >> 8;
            u32t p = atomicAdd(&cur[r], 1u);
            if (p < (u32t)(r + 1) * SEGCAP) {
                sorted[p] = (u32t)s | ((u32t)(d & 255) << 16);
            } else {
                int o = atomicAdd(ovf_cnt, 1);
                if (o < OVF_CAP) ovf[o] = (int)((u32t)s | ((u32t)d << 16));
            }
        }
    } else if (b < NB + EMBB) {
        // ---------------- embed @ W1 ----------------
        int eb = b - NB;
        // stage W1 as packed bf16 pairs: uni[k*16 + col/2]
        for (int i = t; i < 2048; i += 256) {
            float4 v = ((const float4*)W1)[i];
            uni[i * 2 + 0] = (u32t)f2bf(v.x) | ((u32t)f2bf(v.y) << 16);
            uni[i * 2 + 1] = (u32t)f2bf(v.z) | ((u32t)f2bf(v.w) << 16);
        }
        __syncthreads();
        int rg = t >> 3;                 // 0..31 (row within block)
        int cg = t & 7;                  // 0..7  (col group)
        int r = eb * 32 + rg;
        if (r >= NUM_EMBED) return;
        int c0 = cg * 4;
        const float4* E = (const float4*)(embed + (size_t)r * IN_FEATS);
        float4 a = {0.f, 0.f, 0.f, 0.f};
        for (int k4 = 0; k4 < IN_FEATS / 4; ++k4) {
            float4 e4 = E[k4];
            const u32t* wr = uni + (k4 * 4) * 16 + cg * 2;
#define WROW(OFS, S) { \
            u32t ux = wr[(OFS) * 16], uy = wr[(OFS) * 16 + 1]; \
            float w0 = __uint_as_float(ux << 16); \
            float w1 = __uint_as_float(ux & 0xFFFF0000u); \
            float w2 = __uint_as_float(uy << 16); \
            float w3 = __uint_as_float(uy & 0xFFFF0000u); \
            a.x += (S) * w0; a.y += (S) * w1; a.z += (S) * w2; a.w += (S) * w3; }
            WROW(0, e4.x) WROW(1, e4.y) WROW(2, e4.z) WROW(3, e4.w)
#undef WROW
        }
        ushort4 s4 = make_ushort4(f2bf(a.x), f2bf(a.y), f2bf(a.z), f2bf(a.w));
        *(ushort4*)(tmpb + (size_t)r * HID + c0) = s4;
    } else {
        // ---------------- fold ----------------
        int r = b - NB - EMBB;   // 0..64
        int c = t;
        if (r < 32) {
            float acc = 0.f;
            for (int j = 0; j < 256; ++j) acc += W2[r * 256 + j] * Wfc[j * 256 + c];
            M1[r * 256 + c] = acc;
        } else if (r < 64) {
            int k = r - 32;
            float acc = 0.f;
            for (int j = 0; j < 256; ++j) acc += W2[k * 256 + j] * Wfc[(256 + j) * 256 + c];
            M2[k * 256 + c] = acc;
        } else {
            float acc = bfc[c];
            for (int j = 0; j < 256; ++j) acc += b2[j] * (Wfc[j * 256 + c] + Wfc[(256 + j) * 256 + c]);
            bias[c] = acc;
        }
    }
}

// ---------------------------------------------------------------------------
// Phase B (fused):
//   [0, NR)      : pack — segment -> LDS cells [256 nodes][32 u16], flush
//   [NR, NR+4096): gather — feat1[n][:] = tmpb[idx[n]][:]
// ---------------------------------------------------------------------------
__global__ void k_phaseB(const u32t* __restrict__ gcur, const u32t* __restrict__ sorted,
                         int* __restrict__ cnt, u16t* __restrict__ bins,
                         int* __restrict__ ovf_cnt, int* __restrict__ ovf,
                         const u32t* __restrict__ tmpu, const int* __restrict__ idx,
                         u32t* __restrict__ feat1u) {
    __shared__ u16t cells[NR * CAP2];   // 16 KB
    __shared__ u32t cl[NR];             // 1 KB
    int b = blockIdx.x;
    int t = threadIdx.x;
    if (b < NR) {
        int r = b;
        for (int i = t; i < NR * CAP2 / 2; i += 256) ((u32t*)cells)[i] = 0;
        cl[t] = 0;
        __syncthreads();
        u32t beg = (u32t)r * SEGCAP;
        u32t end = min(gcur[r], (u32t)(r + 1) * SEGCAP);
        for (u32t i = beg + t; i < end; i += 256) {
            u32t w = sorted[i];
            int dl = (int)(w >> 16) & 255;
            u32t p = atomicAdd(&cl[dl], 1u);
            if (p < CAP2) {
                cells[dl * CAP2 + p] = (u16t)(w & 0xFFFFu);
            } else {
                int o = atomicAdd(ovf_cnt, 1);
                u32t dfull = ((u32t)r << 8) | (u32t)dl;
                if (o < OVF_CAP) ovf[o] = (int)((w & 0xFFFFu) | (dfull << 16));
            }
        }
        __syncthreads();
        for (int i = t; i < NR * CAP2 / 2; i += 256)
            ((u32t*)(bins + ((size_t)r << 13)))[i] = ((const u32t*)cells)[i];
        cnt[(r << 8) + t] = (int)cl[t];   // true count (may exceed CAP2)
    } else {
        int i = (b - NR) * 256 + t;
        int n = i >> 4, j = i & 15;
        feat1u[((size_t)n << 4) + j] = tmpu[((size_t)idx[n] << 4) + j];
    }
}

// ---------------------------------------------------------------------------
// SpMM1: agg1[v][c] = relu(sum_slots feat1[s][c] + ovf-scan + b1[c])
// Pure store (no pre-zero). Ovf list scanned by all lanes (broadcast, ~tens).
// ---------------------------------------------------------------------------
__global__ void k_spmm1(const u16t* __restrict__ feat1,
                        const int* __restrict__ cnt, const u16t* __restrict__ bins,
                        const int* __restrict__ ovf_cnt, const int* __restrict__ ovf,
                        const float* __restrict__ b1, float* __restrict__ agg1) {
    int t = blockIdx.x * 256 + threadIdx.x;
    int v = t >> 5, c = t & 31;
    int m = cnt[v];
    const int4* cell = (const int4*)(bins + ((size_t)v << 5));
    u32t w[8];
    *(int4*)(w + 0) = cell[0];
    *(int4*)(w + 4) = cell[1];
    float va[16];
#pragma unroll
    for (int k = 0; k < 8; ++k) {
        va[2 * k + 0] = bf2f(feat1[((size_t)(w[k] & 0xFFFFu) << 5) + c]);
        va[2 * k + 1] = bf2f(feat1[((size_t)(w[k] >> 16) << 5) + c]);
    }
    float acc = 0.f;
#pragma unroll
    for (int j = 0; j < 16; ++j) acc += (m > j) ? va[j] : 0.f;
    if (m > 16) {
        u32t w2[8];
        *(int4*)(w2 + 0) = cell[2];
        *(int4*)(w2 + 4) = cell[3];
        float vb[16];
#pragma unroll
        for (int k = 0; k < 8; ++k) {
            vb[2 * k + 0] = bf2f(feat1[((size_t)(w2[k] & 0xFFFFu) << 5) + c]);
            vb[2 * k + 1] = bf2f(feat1[((size_t)(w2[k] >> 16) << 5) + c]);
        }
#pragma unroll
        for (int j = 0; j < 16; ++j) acc += (m > 16 + j) ? vb[j] : 0.f;
    }
    int total = min(*ovf_cnt, OVF_CAP);
    for (int i = 0; i < total; ++i) {
        u32t e = (u32t)ovf[i];
        if ((e >> 16) == (u32t)v)
            acc += bf2f(feat1[((size_t)(e & 0xFFFFu) << 5) + c]);
    }
    agg1[t] = fmaxf(acc + b1[c], 0.f);
}

// ---------------------------------------------------------------------------
// SpMM2 over the 8192 batch slots only (agg1 rows f32, 128B).
// ---------------------------------------------------------------------------
__global__ void k_spmm2b(const float* __restrict__ agg1,
                         const int* __restrict__ cnt, const u16t* __restrict__ bins,
                         const int* __restrict__ ovf_cnt, const int* __restrict__ ovf,
                         const int* __restrict__ g1, const int* __restrict__ g2,
                         float* __restrict__ pairfeat) {
    int t = blockIdx.x * 256 + threadIdx.x;
    int slot = t >> 5, c = t & 31;
    int v = (slot < BATCH) ? g1[slot] : g2[slot - BATCH];
    int m = cnt[v];
    const int4* cell = (const int4*)(bins + ((size_t)v << 5));
    u32t w[8];
    *(int4*)(w + 0) = cell[0];
    *(int4*)(w + 4) = cell[1];
    float va[16];
#pragma unroll
    for (int k = 0; k < 8; ++k) {
        va[2 * k + 0] = agg1[((size_t)(w[k] & 0xFFFFu) << 5) + c];
        va[2 * k + 1] = agg1[((size_t)(w[k] >> 16) << 5) + c];
    }
    float acc = 0.f;
#pragma unroll
    for (int j = 0; j < 16; ++j) acc += (m > j) ? va[j] : 0.f;
    if (m > 16) {
        u32t w2[8];
        *(int4*)(w2 + 0) = cell[2];
        *(int4*)(w2 + 4) = cell[3];
        float vb[16];
#pragma unroll
        for (int k = 0; k < 8; ++k) {
            vb[2 * k + 0] = agg1[((size_t)(w2[k] & 0xFFFFu) << 5) + c];
            vb[2 * k + 1] = agg1[((size_t)(w2[k] >> 16) << 5) + c];
        }
#pragma unroll
        for (int j = 0; j < 16; ++j) acc += (m > 16 + j) ? vb[j] : 0.f;
    }
    int total = min(*ovf_cnt, OVF_CAP);
    for (int i = 0; i < total; ++i) {
        u32t e = (u32t)ovf[i];
        if ((e >> 16) == (u32t)v)
            acc += agg1[((size_t)(e & 0xFFFFu) << 5) + c];
    }
    pairfeat[t] = acc;
}

// ---------------------------------------------------------------------------
// K7: 8 pairs per block; M1/M2 columns shared across the 8 pairs.
// ---------------------------------------------------------------------------
__global__ void k_final(const float* __restrict__ pairfeat,
                        const float* __restrict__ M1, const float* __restrict__ M2,
                        const float* __restrict__ bias,
                        float* __restrict__ out) {
    __shared__ float a1s[8][HID];
    __shared__ float a2s[8][HID];
    int i0 = blockIdx.x * 8;
    int tid = threadIdx.x;
    int p = tid >> 5, w = tid & 31;
    a1s[p][w] = pairfeat[(size_t)(i0 + p) * HID + w];
    a2s[p][w] = pairfeat[(size_t)(BATCH + i0 + p) * HID + w];
    __syncthreads();

    int c = tid;
    float acc[8];
#pragma unroll
    for (int q = 0; q < 8; ++q) acc[q] = bias[c];
#pragma unroll
    for (int k = 0; k < HID; ++k) {
        float m1 = M1[k * 256 + c];
        float m2 = M2[k * 256 + c];
#pragma unroll
        for (int q = 0; q < 8; ++q)
            acc[q] += a1s[q][k] * m1 + a2s[q][k] * m2;
    }
#pragma unroll
    for (int q = 0; q < 8; ++q)
        out[(size_t)(i0 + q) * 256 + c] = fmaxf(acc[q], 0.f);
}

// ---------------------------------------------------------------------------
extern "C" void kernel_launch(void* const* d_in, const int* in_sizes, int n_in,
                              void* d_out, int out_size, void* d_ws, size_t ws_size,
                              hipStream_t stream) {
    const int*   idx   = (const int*)d_in[0];
    const int*   src   = (const int*)d_in[1];
    const int*   dst   = (const int*)d_in[2];
    const int*   g1    = (const int*)d_in[3];
    const int*   g2    = (const int*)d_in[4];
    const float* embed = (const float*)d_in[5];
    const float* W1    = (const float*)d_in[6];
    const float* b1    = (const float*)d_in[7];
    const float* W2    = (const float*)d_in[8];
    const float* b2    = (const float*)d_in[9];
    const float* Wfc   = (const float*)d_in[10];
    const float* bfc   = (const float*)d_in[11];
    float* out = (float*)d_out;

    char* ws = (char*)d_ws;
    u16t*  tmpb     = (u16t*)ws;   ws += (size_t)NUM_EMBED * HID * 2;        // 3.5 MB
    u16t*  feat1    = (u16t*)ws;   ws += (size_t)N_NODES * HID * 2;          // 4 MB
    float* agg1     = (float*)ws;  ws += (size_t)N_NODES * HID * 4;          // 8 MB
    float* pairfeat = (float*)ws;  ws += (size_t)2 * BATCH * HID * 4;        // 1 MB
    float* M1       = (float*)ws;  ws += 32 * 256 * 4;
    float* M2       = (float*)ws;  ws += 32 * 256 * 4;
    float* bias     = (float*)ws;  ws += 256 * 4;
    u32t*  gcur     = (u32t*)ws;   ws += 256 * 4;
    u32t*  sorted   = (u32t*)ws;   ws += (size_t)NR * SEGCAP * 4;            // 4.7 MB
    int*   cnt      = (int*)ws;    ws += (size_t)N_NODES * 4;                // 256 KB
    u16t*  bins     = (u16t*)ws;   ws += (size_t)N_NODES * CAP2 * 2;         // 4 MB
    int*   ovf_cnt  = (int*)ws;    ws += 64;
    int*   ovf      = (int*)ws;    ws += (size_t)OVF_CAP * 4;                // 256 KB

    k_init<<<1, 256, 0, stream>>>(gcur, ovf_cnt);

    k_phaseA<<<NB + EMBB + 65, 256, 0, stream>>>(src, dst, gcur, sorted, ovf_cnt, ovf,
                                                 embed, W1, tmpb,
                                                 W2, b2, Wfc, bfc, M1, M2, bias);

    k_phaseB<<<NR + (N_NODES * 16) / 256, 256, 0, stream>>>(gcur, sorted, cnt, bins,
                                                            ovf_cnt, ovf,
                                                            (const u32t*)tmpb, idx,
                                                            (u32t*)feat1);

    k_spmm1<<<(N_NODES * 32) / 256, 256, 0, stream>>>(feat1, cnt, bins, ovf_cnt, ovf,
                                                      b1, agg1);
    k_spmm2b<<<(2 * BATCH * 32) / 256, 256, 0, stream>>>(agg1, cnt, bins, ovf_cnt, ovf,
                                                         g1, g2, pairfeat);

    k_final<<<BATCH / 8, 256, 0, stream>>>(pairfeat, M1, M2, bias, out);
}